// Round 17
// baseline (532.526 us; speedup 1.0000x reference)
//
#include <hip/hip_runtime.h>
#include <hip/hip_bf16.h>

#define S_DIM 512
#define N_DIM 384
#define CM 64
#define CZ 128
#define HEADS 8
#define DH 32
#define HD 256

typedef __hip_bfloat16 bf16;
typedef long long i64;
typedef __attribute__((ext_vector_type(8))) short bf16x8;
typedef __attribute__((ext_vector_type(4))) float f32x4;

__device__ __forceinline__ float bf2f(bf16 x) { return __bfloat162float(x); }
__device__ __forceinline__ bf16 f2bf(float x) { return __float2bfloat16(x); }
__device__ __forceinline__ short f2bs(float x) {
  bf16 h = __float2bfloat16(x);
  return *reinterpret_cast<short*>(&h);
}

typedef __attribute__((address_space(3))) unsigned int lds_u32;
typedef __attribute__((address_space(1))) const unsigned int gbl_u32;
__device__ __forceinline__ void gl_lds16(const void* g, void* l) {
  __builtin_amdgcn_global_load_lds((gbl_u32*)g, (lds_u32*)l, 16, 0, 0);
}

// ---------------- weight prep: pack [K][N] fp32 -> bf16 MFMA B-fragments ----
// blocks 0..47: six m-path weights; block 48: wz fragment pack
__global__ __launch_bounds__(256) void k_wprep(const float* __restrict__ wm,
                                               const float* __restrict__ wg,
                                               const float* __restrict__ w1,
                                               const float* __restrict__ w2,
                                               const float* __restrict__ wpo,
                                               const float* __restrict__ w3,
                                               const float* __restrict__ wz,
                                               short* __restrict__ dst,
                                               short* __restrict__ wz_f) {
  if (blockIdx.x == 48) {
    int t = threadIdx.x;
    int ks = t >> 6, lane = t & 63, lg = lane >> 4, n = lane & 15;
    short out[8];
#pragma unroll
    for (int j = 0; j < 8; ++j) {
      int k = ks * 32 + lg * 8 + j;
      out[j] = (n < 8) ? f2bs(wz[k * 8 + n]) : (short)0;
    }
    *reinterpret_cast<float4*>(&wz_f[(size_t)t * 8]) =
        *reinterpret_cast<const float4*>(out);
    return;
  }
  int widx = blockIdx.x >> 3;
  const float* src;
  int N;
  if (widx == 0) { src = wm; N = 256; }
  else if (widx == 1) { src = wg; N = 256; }
  else if (widx == 2) { src = w1; N = 256; }
  else if (widx == 3) { src = w2; N = 256; }
  else if (widx == 4) { src = wpo; N = 64; }
  else { src = w3; N = 64; }
  int NF = N >> 4;
  int tg = ((blockIdx.x & 7) << 8) | threadIdx.x;
  int frag = tg >> 6, lane = tg & 63, lg = lane >> 4, l15 = lane & 15;
  int ks = frag / NF, nf = frag - ks * NF;
  short out[8];
#pragma unroll
  for (int j = 0; j < 8; ++j)
    out[j] = f2bs(src[(size_t)(ks * 32 + lg * 8 + j) * N + nf * 16 + l15]);
  *reinterpret_cast<float4*>(&dst[((size_t)widx << 14) + ((size_t)tg << 3)]) =
      *reinterpret_cast<const float4*>(out);
}

// ---------------- LN(z) + pair-bias logits via MFMA -------------------------
__global__ __launch_bounds__(256) void k_zb(const float* __restrict__ z,
                                            const float* __restrict__ w,
                                            const float* __restrict__ b,
                                            const short* __restrict__ wz_f,
                                            float* __restrict__ logits) {
  int blk = blockIdx.x;
  int i = blk / 6, j0 = (blk % 6) * 64;
  __shared__ __align__(16) char zl[16384];  // 64 rows x 256 B, swizzled bf16
  int t = threadIdx.x, wave = t >> 6, lane = t & 63;
  int lg = lane >> 4, l15 = lane & 15;
  float w0 = w[lane], w1 = w[lane + 64], b0 = b[lane], b1 = b[lane + 64];
  int rwb = wave * 16;
  const float* zbase = z + ((size_t)i * N_DIM + j0 + rwb) * CZ;
  for (int rr = 0; rr < 16; ++rr) {
    int row = rwb + rr;
    const float* zr = zbase + (size_t)rr * CZ;
    float v0 = zr[lane], v1 = zr[lane + 64];
    float s = v0 + v1, sq = v0 * v0 + v1 * v1;
#pragma unroll
    for (int off = 32; off; off >>= 1) {
      s += __shfl_xor(s, off);
      sq += __shfl_xor(sq, off);
    }
    float mu = s * (1.0f / CZ);
    float var = sq * (1.0f / CZ) - mu * mu;
    float rs = rsqrtf(var + 1e-5f);
    int sw = (row & 7) << 4;
    *reinterpret_cast<short*>(zl + row * 256 + ((2 * lane) ^ sw)) =
        f2bs((v0 - mu) * rs * w0 + b0);
    *reinterpret_cast<short*>(zl + row * 256 + ((2 * (lane + 64)) ^ sw)) =
        f2bs((v1 - mu) * rs * w1 + b1);
  }
  __syncthreads();
  f32x4 acc = (f32x4){0.f, 0.f, 0.f, 0.f};
  int arow = rwb + l15;
  int asw = (arow & 7) << 4;
#pragma unroll
  for (int ks = 0; ks < 4; ++ks) {
    bf16x8 a = *reinterpret_cast<const bf16x8*>(
        zl + arow * 256 + (((ks * 32 + lg * 8) * 2) ^ asw));
    bf16x8 bfr = *reinterpret_cast<const bf16x8*>(wz_f + ((size_t)ks * 64 + lane) * 8);
    acc = __builtin_amdgcn_mfma_f32_16x16x32_bf16(a, bfr, acc, 0, 0, 0);
  }
  if (l15 < 8) {
    int j = j0 + rwb + lg * 4;
    float4 o4;
    o4.x = acc[0]; o4.y = acc[1]; o4.z = acc[2]; o4.w = acc[3];
    *reinterpret_cast<float4*>(logits + ((size_t)i * 8 + l15) * N_DIM + j) = o4;
  }
}

// ---------------- softmax over j + direct bf16 emit to w8 [h][i][j] ---------
__global__ __launch_bounds__(128) void k_softmax(const float* __restrict__ wb,
                                                 short* __restrict__ w8) {
  int row = blockIdx.x;              // row = i*8 + h
  int i = row >> 3, h = row & 7;
  const float* p = wb + (size_t)row * N_DIM;
  int t = threadIdx.x;
  float a0 = p[t], a1 = p[t + 128], a2 = p[t + 256];
  float mx = fmaxf(a0, fmaxf(a1, a2));
  __shared__ float red[2], red2[2];
#pragma unroll
  for (int off = 32; off; off >>= 1) mx = fmaxf(mx, __shfl_xor(mx, off));
  if ((t & 63) == 0) red[t >> 6] = mx;
  __syncthreads();
  mx = fmaxf(red[0], red[1]);
  float e0 = __expf(a0 - mx), e1 = __expf(a1 - mx), e2 = __expf(a2 - mx);
  float s = e0 + e1 + e2;
#pragma unroll
  for (int off = 32; off; off >>= 1) s += __shfl_xor(s, off);
  if ((t & 63) == 0) red2[t >> 6] = s;
  __syncthreads();
  float inv = 1.0f / (red2[0] + red2[1]);
  short* wr = w8 + ((size_t)h * N_DIM + i) * N_DIM;
  wr[t] = f2bs(e0 * inv);
  wr[t + 128] = f2bs(e1 * inv);
  wr[t + 256] = f2bs(e2 * inv);
}

// ---------------- v = LN(m0) @ wm via MFMA (inline LN), emit vT[h][n][j] ----
__global__ __launch_bounds__(256, 1) void k_vgemm(const float* __restrict__ m0,
                                                  const float* __restrict__ nw,
                                                  const float* __restrict__ nb,
                                                  const short* __restrict__ wm_f,
                                                  short* __restrict__ vT) {
  int blk = blockIdx.x;
  int sblk = blk / 6, j0 = (blk % 6) * 64;
  __shared__ short vt[256 * 64];
  int t = threadIdx.x, wave = t >> 6, lane = t & 63;
  int lg = lane >> 4, l15 = lane & 15;
  size_t rb = (size_t)sblk * N_DIM + j0;
  int rw0 = wave * 16;
  const float* mrow = m0 + (rb + rw0 + l15) * CM;
  float4 x0 = *reinterpret_cast<const float4*>(mrow + lg * 8);
  float4 x1 = *reinterpret_cast<const float4*>(mrow + lg * 8 + 4);
  float4 x2 = *reinterpret_cast<const float4*>(mrow + 32 + lg * 8);
  float4 x3 = *reinterpret_cast<const float4*>(mrow + 32 + lg * 8 + 4);
  float s = x0.x + x0.y + x0.z + x0.w + x1.x + x1.y + x1.z + x1.w +
            x2.x + x2.y + x2.z + x2.w + x3.x + x3.y + x3.z + x3.w;
  float sq = x0.x * x0.x + x0.y * x0.y + x0.z * x0.z + x0.w * x0.w +
             x1.x * x1.x + x1.y * x1.y + x1.z * x1.z + x1.w * x1.w +
             x2.x * x2.x + x2.y * x2.y + x2.z * x2.z + x2.w * x2.w +
             x3.x * x3.x + x3.y * x3.y + x3.z * x3.z + x3.w * x3.w;
  s += __shfl_xor(s, 16); s += __shfl_xor(s, 32);
  sq += __shfl_xor(sq, 16); sq += __shfl_xor(sq, 32);
  float mu = s * (1.0f / CM);
  float var = sq * (1.0f / CM) - mu * mu;
  float rs = rsqrtf(var + 1e-5f);
  float4 g0 = *reinterpret_cast<const float4*>(nw + lg * 8);
  float4 g1 = *reinterpret_cast<const float4*>(nw + lg * 8 + 4);
  float4 g2 = *reinterpret_cast<const float4*>(nw + 32 + lg * 8);
  float4 g3 = *reinterpret_cast<const float4*>(nw + 32 + lg * 8 + 4);
  float4 c0 = *reinterpret_cast<const float4*>(nb + lg * 8);
  float4 c1 = *reinterpret_cast<const float4*>(nb + lg * 8 + 4);
  float4 c2 = *reinterpret_cast<const float4*>(nb + 32 + lg * 8);
  float4 c3 = *reinterpret_cast<const float4*>(nb + 32 + lg * 8 + 4);
  short av[16];
  av[0] = f2bs((x0.x - mu) * rs * g0.x + c0.x);
  av[1] = f2bs((x0.y - mu) * rs * g0.y + c0.y);
  av[2] = f2bs((x0.z - mu) * rs * g0.z + c0.z);
  av[3] = f2bs((x0.w - mu) * rs * g0.w + c0.w);
  av[4] = f2bs((x1.x - mu) * rs * g1.x + c1.x);
  av[5] = f2bs((x1.y - mu) * rs * g1.y + c1.y);
  av[6] = f2bs((x1.z - mu) * rs * g1.z + c1.z);
  av[7] = f2bs((x1.w - mu) * rs * g1.w + c1.w);
  av[8] = f2bs((x2.x - mu) * rs * g2.x + c2.x);
  av[9] = f2bs((x2.y - mu) * rs * g2.y + c2.y);
  av[10] = f2bs((x2.z - mu) * rs * g2.z + c2.z);
  av[11] = f2bs((x2.w - mu) * rs * g2.w + c2.w);
  av[12] = f2bs((x3.x - mu) * rs * g3.x + c3.x);
  av[13] = f2bs((x3.y - mu) * rs * g3.y + c3.y);
  av[14] = f2bs((x3.z - mu) * rs * g3.z + c3.z);
  av[15] = f2bs((x3.w - mu) * rs * g3.w + c3.w);
  bf16x8 a0 = *reinterpret_cast<const bf16x8*>(&av[0]);
  bf16x8 a1 = *reinterpret_cast<const bf16x8*>(&av[8]);
  f32x4 acc[16];
#pragma unroll
  for (int nf = 0; nf < 16; ++nf) acc[nf] = (f32x4){0.f, 0.f, 0.f, 0.f};
#pragma unroll
  for (int nf = 0; nf < 16; ++nf) {
    bf16x8 b0 = *reinterpret_cast<const bf16x8*>(wm_f + ((size_t)nf * 64 + lane) * 8);
    bf16x8 b1 = *reinterpret_cast<const bf16x8*>(wm_f + ((size_t)(16 + nf) * 64 + lane) * 8);
    acc[nf] = __builtin_amdgcn_mfma_f32_16x16x32_bf16(a0, b0, acc[nf], 0, 0, 0);
    acc[nf] = __builtin_amdgcn_mfma_f32_16x16x32_bf16(a1, b1, acc[nf], 0, 0, 0);
  }
#pragma unroll
  for (int nf = 0; nf < 16; ++nf)
#pragma unroll
    for (int r = 0; r < 4; ++r) {
      int jl = rw0 + lg * 4 + r;
      int hd = nf * 16 + l15;
      vt[hd * 64 + jl] = f2bs(acc[nf][r]);
    }
  __syncthreads();
  int h = t >> 5, d = t & 31;
  size_t gbase = ((size_t)h * 16384 + (size_t)sblk * 32 + d) * 384 + j0;
#pragma unroll
  for (int q = 0; q < 8; ++q)
    *reinterpret_cast<float4*>(&vT[gbase + q * 8]) =
        *reinterpret_cast<const float4*>(&vt[t * 64 + q * 8]);
}

// ---------------- o = W @ V per head, MFMA, dbuf prefetch (BJ=32) -----------
__global__ __launch_bounds__(256, 2) void k_ogemm(const short* __restrict__ w8,
                                                  const short* __restrict__ vT,
                                                  bf16* __restrict__ o) {
  int h = blockIdx.y;
  int u = blockIdx.x;
  int gid = (u & 7) * 24 + (u >> 3);   // bijective XCD chunking (192 = 8*24)
  int nb = gid / 3, ib = gid % 3;
  int i0 = ib * 128;
  __shared__ __align__(16) char lds8[49152];  // W: 2x8KB @0, V: 2x16KB @16384
  char* LW = lds8;
  char* LV = lds8 + 16384;
  int t = threadIdx.x, wave = t >> 6, lane = t & 63;
  int lg = lane >> 4, l15 = lane & 15;
  f32x4 acc[8][4];
#pragma unroll
  for (int a = 0; a < 8; ++a)
#pragma unroll
    for (int b = 0; b < 4; ++b) acc[a][b] = (f32x4){0.f, 0.f, 0.f, 0.f};
  const short* Wb = w8 + ((size_t)h * N_DIM + i0) * N_DIM;
  const short* Vb = vT + ((size_t)h * 16384 + (size_t)nb * 256) * N_DIM;

  auto STAGE = [&](int buf, int kt) {
    int j0 = kt * 32;
#pragma unroll
    for (int q = 0; q < 2; ++q) {
      int c = t + q * 256;
      int ri = c >> 2, s = c & 3;
      gl_lds16(Wb + (size_t)ri * N_DIM + j0 + ((s ^ (ri & 3)) << 3),
               LW + buf * 8192 + c * 16);
    }
#pragma unroll
    for (int q = 0; q < 4; ++q) {
      int c = t + q * 256;
      int rn = c >> 2, s = c & 3;
      gl_lds16(Vb + (size_t)rn * N_DIM + j0 + ((s ^ (rn & 3)) << 3),
               LV + buf * 16384 + c * 16);
    }
  };

  STAGE(0, 0);
  __syncthreads();
  for (int kt = 0; kt < 12; ++kt) {
    int cur = kt & 1;
    if (kt < 11) STAGE(cur ^ 1, kt + 1);
    bf16x8 bfr[4];
#pragma unroll
    for (int fn = 0; fn < 4; ++fn) {
      int nl = wave * 64 + fn * 16 + l15;
      bfr[fn] = *reinterpret_cast<const bf16x8*>(
          LV + cur * 16384 + nl * 64 + ((lg * 16) ^ ((nl & 3) << 4)));
    }
#pragma unroll
    for (int fm = 0; fm < 8; ++fm) {
      int il = fm * 16 + l15;
      bf16x8 af = *reinterpret_cast<const bf16x8*>(
          LW + cur * 8192 + il * 64 + ((lg * 16) ^ ((il & 3) << 4)));
#pragma unroll
      for (int fn = 0; fn < 4; ++fn)
        acc[fm][fn] = __builtin_amdgcn_mfma_f32_16x16x32_bf16(
            af, bfr[fn], acc[fm][fn], 0, 0, 0);
    }
    __syncthreads();
  }
#pragma unroll
  for (int fm = 0; fm < 8; ++fm)
#pragma unroll
    for (int fn = 0; fn < 4; ++fn)
#pragma unroll
      for (int r = 0; r < 4; ++r) {
        int i = i0 + fm * 16 + lg * 4 + r;
        int n = nb * 256 + wave * 64 + fn * 16 + l15;
        int s = n >> 5, d = n & 31;
        o[((size_t)s * N_DIM + i) * HD + h * DH + d] = f2bf(acc[fm][fn][r]);
      }
}

// ---------------- pwa out: inline LN; o staged via LDS; MFMA x2 -------------
#define OSTR 264
__global__ __launch_bounds__(256, 1) void k_pwa_out(const float* __restrict__ m0,
                                                    const bf16* __restrict__ o,
                                                    const float* __restrict__ nw,
                                                    const float* __restrict__ nb,
                                                    const short* __restrict__ wg_f,
                                                    const short* __restrict__ wpo_f,
                                                    float* __restrict__ m1out) {
  int blk = blockIdx.x;
  int sblk = blk / 6, j0 = (blk % 6) * 64;
  __shared__ __align__(16) short olds[64 * OSTR];   // 33,792 B (padded o tile)
  __shared__ __align__(16) char hlds[32768];
  int t = threadIdx.x, wave = t >> 6, lane = t & 63;
  int lg = lane >> 4, l15 = lane & 15;
  size_t rb0 = (size_t)sblk * N_DIM + j0;
  size_t rb = rb0 + wave * 16;
#pragma unroll
  for (int q = 0; q < 8; ++q) {
    int f = t + q * 256;
    int row = f >> 5, pos = f & 31;
    *reinterpret_cast<float4*>(&olds[row * OSTR + pos * 8]) =
        *reinterpret_cast<const float4*>((const short*)o + (rb0 + row) * HD + pos * 8);
  }
  const float* mrow = m0 + (rb + l15) * CM;
  float4 x0 = *reinterpret_cast<const float4*>(mrow + lg * 8);
  float4 x1 = *reinterpret_cast<const float4*>(mrow + lg * 8 + 4);
  float4 x2 = *reinterpret_cast<const float4*>(mrow + 32 + lg * 8);
  float4 x3 = *reinterpret_cast<const float4*>(mrow + 32 + lg * 8 + 4);
  float s = x0.x + x0.y + x0.z + x0.w + x1.x + x1.y + x1.z + x1.w +
            x2.x + x2.y + x2.z + x2.w + x3.x + x3.y + x3.z + x3.w;
  float sq = x0.x * x0.x + x0.y * x0.y + x0.z * x0.z + x0.w * x0.w +
             x1.x * x1.x + x1.y * x1.y + x1.z * x1.z + x1.w * x1.w +
             x2.x * x2.x + x2.y * x2.y + x2.z * x2.z + x2.w * x2.w +
             x3.x * x3.x + x3.y * x3.y + x3.z * x3.z + x3.w * x3.w;
  s += __shfl_xor(s, 16); s += __shfl_xor(s, 32);
  sq += __shfl_xor(sq, 16); sq += __shfl_xor(sq, 32);
  float mu = s * (1.0f / CM);
  float var = sq * (1.0f / CM) - mu * mu;
  float rs = rsqrtf(var + 1e-5f);
  float4 g0 = *reinterpret_cast<const float4*>(nw + lg * 8);
  float4 g1 = *reinterpret_cast<const float4*>(nw + lg * 8 + 4);
  float4 g2 = *reinterpret_cast<const float4*>(nw + 32 + lg * 8);
  float4 g3 = *reinterpret_cast<const float4*>(nw + 32 + lg * 8 + 4);
  float4 c0 = *reinterpret_cast<const float4*>(nb + lg * 8);
  float4 c1 = *reinterpret_cast<const float4*>(nb + lg * 8 + 4);
  float4 c2 = *reinterpret_cast<const float4*>(nb + 32 + lg * 8);
  float4 c3 = *reinterpret_cast<const float4*>(nb + 32 + lg * 8 + 4);
  short av[16];
  av[0] = f2bs((x0.x - mu) * rs * g0.x + c0.x);
  av[1] = f2bs((x0.y - mu) * rs * g0.y + c0.y);
  av[2] = f2bs((x0.z - mu) * rs * g0.z + c0.z);
  av[3] = f2bs((x0.w - mu) * rs * g0.w + c0.w);
  av[4] = f2bs((x1.x - mu) * rs * g1.x + c1.x);
  av[5] = f2bs((x1.y - mu) * rs * g1.y + c1.y);
  av[6] = f2bs((x1.z - mu) * rs * g1.z + c1.z);
  av[7] = f2bs((x1.w - mu) * rs * g1.w + c1.w);
  av[8] = f2bs((x2.x - mu) * rs * g2.x + c2.x);
  av[9] = f2bs((x2.y - mu) * rs * g2.y + c2.y);
  av[10] = f2bs((x2.z - mu) * rs * g2.z + c2.z);
  av[11] = f2bs((x2.w - mu) * rs * g2.w + c2.w);
  av[12] = f2bs((x3.x - mu) * rs * g3.x + c3.x);
  av[13] = f2bs((x3.y - mu) * rs * g3.y + c3.y);
  av[14] = f2bs((x3.z - mu) * rs * g3.z + c3.z);
  av[15] = f2bs((x3.w - mu) * rs * g3.w + c3.w);
  bf16x8 a0 = *reinterpret_cast<const bf16x8*>(&av[0]);
  bf16x8 a1 = *reinterpret_cast<const bf16x8*>(&av[8]);
  f32x4 acc[16];
#pragma unroll
  for (int nf = 0; nf < 16; ++nf) acc[nf] = (f32x4){0.f, 0.f, 0.f, 0.f};
#pragma unroll
  for (int nf = 0; nf < 16; ++nf) {
    bf16x8 b0 = *reinterpret_cast<const bf16x8*>(wg_f + ((size_t)nf * 64 + lane) * 8);
    bf16x8 b1 = *reinterpret_cast<const bf16x8*>(wg_f + ((size_t)(16 + nf) * 64 + lane) * 8);
    acc[nf] = __builtin_amdgcn_mfma_f32_16x16x32_bf16(a0, b0, acc[nf], 0, 0, 0);
    acc[nf] = __builtin_amdgcn_mfma_f32_16x16x32_bf16(a1, b1, acc[nf], 0, 0, 0);
  }
  __syncthreads();  // olds staged (all waves), safe to read
  char* hb = hlds + wave * 8192;
#pragma unroll
  for (int nf = 0; nf < 16; ++nf)
#pragma unroll
    for (int r = 0; r < 4; ++r) {
      int row = lg * 4 + r;
      float x = acc[nf][r];
      float g = 1.0f / (1.0f + __expf(-x));
      float ov = bf2f(*reinterpret_cast<const bf16*>(
          &olds[(wave * 16 + row) * OSTR + nf * 16 + l15]));
      *reinterpret_cast<short*>(
          hb + row * 512 + (((nf * 16 + l15) * 2) ^ ((row & 7) << 4))) = f2bs(g * ov);
    }
  __syncthreads();
  f32x4 acc3[4];
#pragma unroll
  for (int nf2 = 0; nf2 < 4; ++nf2) acc3[nf2] = (f32x4){0.f, 0.f, 0.f, 0.f};
#pragma unroll
  for (int ks2 = 0; ks2 < 8; ++ks2) {
    bf16x8 a2 = *reinterpret_cast<const bf16x8*>(
        hb + l15 * 512 + ((ks2 * 64 + lg * 16) ^ ((l15 & 7) << 4)));
#pragma unroll
    for (int nf2 = 0; nf2 < 4; ++nf2) {
      bf16x8 b = *reinterpret_cast<const bf16x8*>(
          wpo_f + ((size_t)(ks2 * 4 + nf2) * 64 + lane) * 8);
      acc3[nf2] = __builtin_amdgcn_mfma_f32_16x16x32_bf16(a2, b, acc3[nf2], 0, 0, 0);
    }
  }
#pragma unroll
  for (int nf2 = 0; nf2 < 4; ++nf2)
#pragma unroll
    for (int r = 0; r < 4; ++r) {
      size_t a = (rb + lg * 4 + r) * CM + nf2 * 16 + l15;
      m1out[a] = m0[a] + acc3[nf2][r];
    }
}

// ---------------- transition via MFMA: m2 = m1 + (silu(tn@w1)*(tn@w2))@w3 ---
__global__ __launch_bounds__(256, 1) void k_transition(const float* __restrict__ nw,
                                                       const float* __restrict__ nb,
                                                       const short* __restrict__ w1_f,
                                                       const short* __restrict__ w2_f,
                                                       const short* __restrict__ w3_f,
                                                       float* __restrict__ mio) {
  __shared__ __align__(16) char hlds[32768];
  int t = threadIdx.x, wave = t >> 6, lane = t & 63;
  int lg = lane >> 4, l15 = lane & 15;
  size_t rb = (size_t)blockIdx.x * 64 + wave * 16;
  const float* mrow = mio + (rb + l15) * CM;
  float4 x0 = *reinterpret_cast<const float4*>(mrow + lg * 8);
  float4 x1 = *reinterpret_cast<const float4*>(mrow + lg * 8 + 4);
  float4 x2 = *reinterpret_cast<const float4*>(mrow + 32 + lg * 8);
  float4 x3 = *reinterpret_cast<const float4*>(mrow + 32 + lg * 8 + 4);
  float s = x0.x + x0.y + x0.z + x0.w + x1.x + x1.y + x1.z + x1.w +
            x2.x + x2.y + x2.z + x2.w + x3.x + x3.y + x3.z + x3.w;
  float sq = x0.x * x0.x + x0.y * x0.y + x0.z * x0.z + x0.w * x0.w +
             x1.x * x1.x + x1.y * x1.y + x1.z * x1.z + x1.w * x1.w +
             x2.x * x2.x + x2.y * x2.y + x2.z * x2.z + x2.w * x2.w +
             x3.x * x3.x + x3.y * x3.y + x3.z * x3.z + x3.w * x3.w;
  s += __shfl_xor(s, 16); s += __shfl_xor(s, 32);
  sq += __shfl_xor(sq, 16); sq += __shfl_xor(sq, 32);
  float mu = s * (1.0f / CM);
  float var = sq * (1.0f / CM) - mu * mu;
  float rs = rsqrtf(var + 1e-5f);
  float4 g0 = *reinterpret_cast<const float4*>(nw + lg * 8);
  float4 g1 = *reinterpret_cast<const float4*>(nw + lg * 8 + 4);
  float4 g2 = *reinterpret_cast<const float4*>(nw + 32 + lg * 8);
  float4 g3 = *reinterpret_cast<const float4*>(nw + 32 + lg * 8 + 4);
  float4 c0 = *reinterpret_cast<const float4*>(nb + lg * 8);
  float4 c1 = *reinterpret_cast<const float4*>(nb + lg * 8 + 4);
  float4 c2 = *reinterpret_cast<const float4*>(nb + 32 + lg * 8);
  float4 c3 = *reinterpret_cast<const float4*>(nb + 32 + lg * 8 + 4);
  short av[16];
  av[0] = f2bs((x0.x - mu) * rs * g0.x + c0.x);
  av[1] = f2bs((x0.y - mu) * rs * g0.y + c0.y);
  av[2] = f2bs((x0.z - mu) * rs * g0.z + c0.z);
  av[3] = f2bs((x0.w - mu) * rs * g0.w + c0.w);
  av[4] = f2bs((x1.x - mu) * rs * g1.x + c1.x);
  av[5] = f2bs((x1.y - mu) * rs * g1.y + c1.y);
  av[6] = f2bs((x1.z - mu) * rs * g1.z + c1.z);
  av[7] = f2bs((x1.w - mu) * rs * g1.w + c1.w);
  av[8] = f2bs((x2.x - mu) * rs * g2.x + c2.x);
  av[9] = f2bs((x2.y - mu) * rs * g2.y + c2.y);
  av[10] = f2bs((x2.z - mu) * rs * g2.z + c2.z);
  av[11] = f2bs((x2.w - mu) * rs * g2.w + c2.w);
  av[12] = f2bs((x3.x - mu) * rs * g3.x + c3.x);
  av[13] = f2bs((x3.y - mu) * rs * g3.y + c3.y);
  av[14] = f2bs((x3.z - mu) * rs * g3.z + c3.z);
  av[15] = f2bs((x3.w - mu) * rs * g3.w + c3.w);
  bf16x8 a0 = *reinterpret_cast<const bf16x8*>(&av[0]);
  bf16x8 a1 = *reinterpret_cast<const bf16x8*>(&av[8]);
  f32x4 acc1[16], acc2[16];
#pragma unroll
  for (int nf = 0; nf < 16; ++nf) {
    acc1[nf] = (f32x4){0.f, 0.f, 0.f, 0.f};
    acc2[nf] = (f32x4){0.f, 0.f, 0.f, 0.f};
  }
#pragma unroll
  for (int nf = 0; nf < 16; ++nf) {
    bf16x8 b10 = *reinterpret_cast<const bf16x8*>(w1_f + ((size_t)nf * 64 + lane) * 8);
    bf16x8 b11 = *reinterpret_cast<const bf16x8*>(w1_f + ((size_t)(16 + nf) * 64 + lane) * 8);
    acc1[nf] = __builtin_amdgcn_mfma_f32_16x16x32_bf16(a0, b10, acc1[nf], 0, 0, 0);
    acc1[nf] = __builtin_amdgcn_mfma_f32_16x16x32_bf16(a1, b11, acc1[nf], 0, 0, 0);
    bf16x8 b20 = *reinterpret_cast<const bf16x8*>(w2_f + ((size_t)nf * 64 + lane) * 8);
    bf16x8 b21 = *reinterpret_cast<const bf16x8*>(w2_f + ((size_t)(16 + nf) * 64 + lane) * 8);
    acc2[nf] = __builtin_amdgcn_mfma_f32_16x16x32_bf16(a0, b20, acc2[nf], 0, 0, 0);
    acc2[nf] = __builtin_amdgcn_mfma_f32_16x16x32_bf16(a1, b21, acc2[nf], 0, 0, 0);
  }
  char* hb = hlds + wave * 8192;
#pragma unroll
  for (int nf = 0; nf < 16; ++nf)
#pragma unroll
    for (int r = 0; r < 4; ++r) {
      int row = lg * 4 + r;
      float x = acc1[nf][r];
      float h = (x / (1.0f + __expf(-x))) * acc2[nf][r];
      *reinterpret_cast<short*>(
          hb + row * 512 + (((nf * 16 + l15) * 2) ^ ((row & 7) << 4))) = f2bs(h);
    }
  __syncthreads();
  f32x4 acc3[4];
#pragma unroll
  for (int nf2 = 0; nf2 < 4; ++nf2) acc3[nf2] = (f32x4){0.f, 0.f, 0.f, 0.f};
#pragma unroll
  for (int ks2 = 0; ks2 < 8; ++ks2) {
    bf16x8 a2 = *reinterpret_cast<const bf16x8*>(
        hb + l15 * 512 + ((ks2 * 64 + lg * 16) ^ ((l15 & 7) << 4)));
#pragma unroll
    for (int nf2 = 0; nf2 < 4; ++nf2) {
      bf16x8 b = *reinterpret_cast<const bf16x8*>(
          w3_f + ((size_t)(ks2 * 4 + nf2) * 64 + lane) * 8);
      acc3[nf2] = __builtin_amdgcn_mfma_f32_16x16x32_bf16(a2, b, acc3[nf2], 0, 0, 0);
    }
  }
#pragma unroll
  for (int nf2 = 0; nf2 < 4; ++nf2)
#pragma unroll
    for (int r = 0; r < 4; ++r) {
      size_t a = (rb + lg * 4 + r) * CM + nf2 * 16 + l15;
      mio[a] = mio[a] + acc3[nf2][r];
    }
}

// ---------------- opm a/b: LN(m2)@wa/wb -> fp8 e4m3, FRAGMENT-PACKED --------
__global__ __launch_bounds__(256) void k_opm_ab(const float* __restrict__ m2,
                                                const float* __restrict__ nw,
                                                const float* __restrict__ nb,
                                                const float* __restrict__ wa,
                                                const float* __restrict__ wb,
                                                unsigned char* __restrict__ at8,
                                                unsigned char* __restrict__ bt8) {
  int bix = blockIdx.x;
  int sg = bix / N_DIM;
  int i = bix - sg * N_DIM;
  __shared__ float on[64][65];
  __shared__ float wl[2][64][36];
  __shared__ float tl[2][32][65];
  int t = threadIdx.x, w = t >> 6, lane = t & 63;
  float gw = nw[lane], gb = nb[lane];
  for (int rr = 0; rr < 16; ++rr) {
    int sl = w * 16 + rr;
    float x = m2[((size_t)(sg * 64 + sl) * N_DIM + i) * CM + lane];
    float s = x, sq = x * x;
#pragma unroll
    for (int off = 32; off; off >>= 1) {
      s += __shfl_xor(s, off);
      sq += __shfl_xor(sq, off);
    }
    float mu = s * (1.0f / CM);
    float var = sq * (1.0f / CM) - mu * mu;
    float rs = rsqrtf(var + 1e-5f);
    on[sl][lane] = (x - mu) * rs * gw + gb;
  }
  for (int idx = t; idx < 2048; idx += 256) {
    int k = idx >> 5, c = idx & 31;
    wl[0][k][c] = wa[idx];
    wl[1][k][c] = wb[idx];
  }
  __syncthreads();
  int s = t >> 2, c0 = (t & 3) * 8;
  float accA[8], accB[8];
#pragma unroll
  for (int j = 0; j < 8; ++j) { accA[j] = 0.0f; accB[j] = 0.0f; }
  for (int k = 0; k < 64; ++k) {
    float ov = on[s][k];
#pragma unroll
    for (int j = 0; j < 8; ++j) {
      accA[j] += ov * wl[0][k][c0 + j];
      accB[j] += ov * wl[1][k][c0 + j];
    }
  }
#pragma unroll
  for (int j = 0; j < 8; ++j) {
    tl[0][c0 + j][s] = accA[j];
    tl[1][c0 + j][s] = accB[j];
  }
  __syncthreads();
  int cc = t >> 3, s8 = (t & 7) * 8;
  int lane8 = ((((s8 & 31) >> 3) * 16) + (cc & 15)) * 8;
  int kg = sg * 2 + (s8 >> 5);
  size_t obA = (size_t)(i >> 3) * 131072 + (size_t)kg * 8192 +
               (size_t)((i & 7) * 2 + (cc >> 4)) * 512 + lane8;
  size_t obB = (size_t)(i >> 2) * 65536 + (size_t)kg * 4096 +
               (size_t)((i & 3) * 2 + (cc >> 4)) * 512 + lane8;
  unsigned int p0 = 0, p1 = 0;
  p0 = __builtin_amdgcn_cvt_pk_fp8_f32(tl[0][cc][s8 + 0], tl[0][cc][s8 + 1], p0, false);
  p0 = __builtin_amdgcn_cvt_pk_fp8_f32(tl[0][cc][s8 + 2], tl[0][cc][s8 + 3], p0, true);
  p1 = __builtin_amdgcn_cvt_pk_fp8_f32(tl[0][cc][s8 + 4], tl[0][cc][s8 + 5], p1, false);
  p1 = __builtin_amdgcn_cvt_pk_fp8_f32(tl[0][cc][s8 + 6], tl[0][cc][s8 + 7], p1, true);
  uint2 pa = {p0, p1};
  *reinterpret_cast<uint2*>(at8 + obA) = pa;
  p0 = 0; p1 = 0;
  p0 = __builtin_amdgcn_cvt_pk_fp8_f32(tl[1][cc][s8 + 0], tl[1][cc][s8 + 1], p0, false);
  p0 = __builtin_amdgcn_cvt_pk_fp8_f32(tl[1][cc][s8 + 2], tl[1][cc][s8 + 3], p0, true);
  p1 = __builtin_amdgcn_cvt_pk_fp8_f32(tl[1][cc][s8 + 4], tl[1][cc][s8 + 5], p1, false);
  p1 = __builtin_amdgcn_cvt_pk_fp8_f32(tl[1][cc][s8 + 6], tl[1][cc][s8 + 7], p1, true);
  uint2 pb = {p0, p1};
  *reinterpret_cast<uint2*>(bt8 + obB) = pb;
}

// ---------------- wo8: fragment-packed wo (fp8 e4m3), permuted k=(d<<5)|c ---
__global__ __launch_bounds__(256) void k_wot(const float* __restrict__ wo,
                                             unsigned char* __restrict__ wo8) {
  int tg = blockIdx.x * 256 + threadIdx.x;   // 64 blocks -> 16384 fragments
  int frag = tg >> 6, lane = tg & 63;
  int eblk = frag >> 5, kc = frag & 31;
  int e = eblk * 16 + (lane & 15);
  int kbase = kc * 32 + (lane >> 4) * 8;
  float v[8];
#pragma unroll
  for (int j = 0; j < 8; ++j) {
    int q = kbase + j;                       // permuted index cd2 = (d<<5)|c
    int row = ((q & 31) << 5) | (q >> 5);    // original wo row = c*32 + d
    v[j] = wo[(size_t)row * CZ + e];
  }
  unsigned int p0 = 0, p1 = 0;
  p0 = __builtin_amdgcn_cvt_pk_fp8_f32(v[0], v[1], p0, false);
  p0 = __builtin_amdgcn_cvt_pk_fp8_f32(v[2], v[3], p0, true);
  p1 = __builtin_amdgcn_cvt_pk_fp8_f32(v[4], v[5], p1, false);
  p1 = __builtin_amdgcn_cvt_pk_fp8_f32(v[6], v[7], p1, true);
  uint2 pk = {p0, p1};
  *reinterpret_cast<uint2*>(wo8 + (size_t)tg * 8) = pk;
}

// ---------------- OPM: fp8 MFMA 256x128, fragment LDS, fp8 P epilogue -------
// launch_bounds(512,3): 3 blocks/CU (CUDA min-blocks semantics on this hipcc;
// LDS 48KB*3=144KB fits, VGPR cap 85 > 56 used) -> 24 waves/CU latency hiding
#define PS 1064   // P row stride bytes (266 dwords; gcd(266,32)=2 -> ~free)
__global__ __launch_bounds__(512, 3) void k_opm(const unsigned char* __restrict__ at8,
                                                const unsigned char* __restrict__ bt8,
                                                const unsigned char* __restrict__ wo8,
                                                const float* __restrict__ bo,
                                                const float* __restrict__ z0,
                                                float* __restrict__ z1) {
  // XCD mapping: xcd owns bm in [xcd*6, xcd*6+6), traversal bn-outer (4608=8*576)
  int g = blockIdx.x;
  int xcd = g & 7, u = g >> 3;
  int bn = u / 6;
  int bm = xcd * 6 + (u - bn * 6);
  // A: 2x16KB @0, B: 2x8KB @32768; P fp8 (32 x 1064 = 34048 B) overlays
  __shared__ __align__(16) char lds8[49152];
  char* LA = lds8;
  char* LB = lds8 + 32768;
  int t = threadIdx.x, wave = t >> 6, lane = t & 63;
  int wm2 = wave >> 1, wn2 = wave & 1;   // 4m x 2n wave grid, 64x64 tiles
  int lg = lane >> 4, l15 = lane & 15;
  f32x4 acc[4][4];
#pragma unroll
  for (int a = 0; a < 4; ++a)
#pragma unroll
    for (int b = 0; b < 4; ++b) acc[a][b] = (f32x4){0.f, 0.f, 0.f, 0.f};
  const unsigned char* A = at8 + (size_t)bm * 131072;   // [kg16][mg16][512]
  const unsigned char* B = bt8 + (size_t)bn * 65536;    // [kg16][ng8][512]

  auto STAGE = [&](int buf, int kt) {
    gl_lds16(A + (size_t)kt * 16384 + t * 16, LA + buf * 16384 + t * 16);
    gl_lds16(A + (size_t)kt * 16384 + 8192 + t * 16,
             LA + buf * 16384 + 8192 + t * 16);
    gl_lds16(B + (size_t)kt * 8192 + t * 16, LB + buf * 8192 + t * 16);
  };

  STAGE(0, 0);
  __syncthreads();
  for (int kt = 0; kt < 8; ++kt) {
    int cur = kt & 1;
    if (kt < 7) STAGE(cur ^ 1, kt + 1);
    const char* LAc = LA + cur * 16384;
    const char* LBc = LB + cur * 8192;
#pragma unroll
    for (int ks = 0; ks < 2; ++ks) {
      i64 bfr[4];
#pragma unroll
      for (int fn = 0; fn < 4; ++fn)
        bfr[fn] = *reinterpret_cast<const i64*>(
            LBc + ks * 4096 + (wn2 * 4 + fn) * 512 + lane * 8);
#pragma unroll
      for (int fm = 0; fm < 4; ++fm) {
        i64 af = *reinterpret_cast<const i64*>(
            LAc + ks * 8192 + (wm2 * 4 + fm) * 512 + lane * 8);
#pragma unroll
        for (int fn = 0; fn < 4; ++fn)
          acc[fm][fn] = __builtin_amdgcn_mfma_f32_16x16x32_fp8_fp8(
              af, bfr[fn], acc[fm][fn], 0, 0, 0);
      }
    }
    __syncthreads();
  }

  // --- one-shot P write (fp8, scaled x1024/512=2): P[32 pairs][PS bytes] ---
  unsigned char* P = (unsigned char*)lds8;
  const float sc = 2.0f;          // op*1024 when combined with 1/512
#pragma unroll
  for (int fm = 0; fm < 4; ++fm)
#pragma unroll
    for (int fn = 0; fn < 4; ++fn) {
      int m = wm2 * 64 + fm * 16 + lg * 4;   // 4 consecutive m (r)
      int n = wn2 * 64 + fn * 16 + l15;
      int prow = (m >> 5) * 4 + (n >> 5);
      int cd2 = ((n & 31) << 5) | (m & 31);
      unsigned int p0 = 0;
      p0 = __builtin_amdgcn_cvt_pk_fp8_f32(acc[fm][fn][0] * sc,
                                           acc[fm][fn][1] * sc, p0, false);
      p0 = __builtin_amdgcn_cvt_pk_fp8_f32(acc[fm][fn][2] * sc,
                                           acc[fm][fn][3] * sc, p0, true);
      *reinterpret_cast<unsigned int*>(P + prow * PS + cd2) = p0;
    }
  __syncthreads();

  // --- projection (fp8 x fp8): 2 pair-groups x 8 e-blocks, 8 waves ---
  int eblk = wave;
#pragma unroll
  for (int it = 0; it < 2; ++it) {
    f32x4 pacc = (f32x4){0.f, 0.f, 0.f, 0.f};
    for (int c0 = 0; c0 < 1024; c0 += 32) {
      i64 pa = *reinterpret_cast<const i64*>(
          P + (it * 16 + l15) * PS + c0 + lg * 8);
      i64 pb = *reinterpret_cast<const i64*>(
          wo8 + ((size_t)(eblk * 32 + (c0 >> 5)) * 64 + lane) * 8);
      pacc = __builtin_amdgcn_mfma_f32_16x16x32_fp8_fp8(pa, pb, pacc, 0, 0, 0);
    }
    int e = eblk * 16 + l15;
    float bov = bo[e];
#pragma unroll
    for (int r = 0; r < 4; ++r) {
      int prow = it * 16 + lg * 4 + r;
      int gi = bm * 8 + (prow >> 2), gj = bn * 4 + (prow & 3);
      size_t addr = ((size_t)gi * N_DIM + gj) * CZ + e;
      z1[addr] = z0[addr] + pacc[r] * (1.0f / 1024.0f) + bov;
    }
  }
}

// ---------------------------------------------------------------------------
extern "C" void kernel_launch(void* const* d_in, const int* in_sizes, int n_in,
                              void* d_out, int out_size, void* d_ws, size_t ws_size,
                              hipStream_t stream) {
  const float* m0 = (const float*)d_in[0];
  const float* z0 = (const float*)d_in[1];
  const float* pwa_nm_w = (const float*)d_in[2];
  const float* pwa_nm_b = (const float*)d_in[3];
  const float* pwa_nz_w = (const float*)d_in[4];
  const float* pwa_nz_b = (const float*)d_in[5];
  const float* pwa_wm = (const float*)d_in[6];
  const float* pwa_wg = (const float*)d_in[7];
  const float* pwa_wz = (const float*)d_in[8];
  const float* pwa_wo = (const float*)d_in[9];
  const float* tr_nw = (const float*)d_in[10];
  const float* tr_nb = (const float*)d_in[11];
  const float* tr_w1 = (const float*)d_in[12];
  const float* tr_w2 = (const float*)d_in[13];
  const float* tr_w3 = (const float*)d_in[14];
  const float* opm_nw = (const float*)d_in[15];
  const float* opm_nb = (const float*)d_in[16];
  const float* opm_wa = (const float*)d_in[17];
  const float* opm_wb = (const float*)d_in[18];
  const float* opm_wo = (const float*)d_in[19];
  const float* opm_bo = (const float*)d_in[20];

  char* ws = (char*)d_ws;
  float* wbuf = (float*)(ws + 25165824);         //  4,718,592 B
  short* vT = (short*)(ws + 29884416);           // 100,663,296 B
  bf16* o = (bf16*)(ws + 130547712);             // 100,663,296 B
  // reuse dead vT region after k_ogemm:
  unsigned char* at8 = (unsigned char*)(ws + 29884416);  // 6,291,456 B
  unsigned char* bt8 = at8 + 6291456;                    // 6,291,456 B
  unsigned char* wo8 = (unsigned char*)(ws + 55050240);  //   131,072 B
  short* wz_f = (short*)(ws + 55312384);                 //     4,096 B

  float* m_out = (float*)d_out;
  float* z1 = m_out + (size_t)S_DIM * N_DIM * CM;
  // scratch in the z1 region of d_out (dead until k_opm overwrites all of z1)
  short* packW = (short*)z1;                     // 6 x 32 KB
  short* wm_f = packW;
  short* wg_f = packW + 16384;
  short* w1_f = packW + 32768;
  short* w2_f = packW + 49152;
  short* wpo_f = packW + 65536;
  short* w3_f = packW + 81920;
  short* w8 = (short*)((char*)z1 + 262144);      // 2,359,296 B (bf16 softmax W)

  k_wprep<<<49, 256, 0, stream>>>(pwa_wm, pwa_wg, tr_w1, tr_w2, pwa_wo, tr_w3,
                                  pwa_wz, packW, wz_f);
  k_zb<<<2304, 256, 0, stream>>>(z0, pwa_nz_w, pwa_nz_b, wz_f, wbuf);
  k_softmax<<<3072, 128, 0, stream>>>(wbuf, w8);
  k_vgemm<<<3072, 256, 0, stream>>>(m0, pwa_nm_w, pwa_nm_b, wm_f, vT);
  k_ogemm<<<dim3(192, 8), 256, 0, stream>>>(w8, vT, o);
  k_pwa_out<<<3072, 256, 0, stream>>>(m0, o, pwa_nm_w, pwa_nm_b, wg_f, wpo_f, m_out);
  k_wot<<<64, 256, 0, stream>>>(opm_wo, wo8);
  k_transition<<<3072, 256, 0, stream>>>(tr_nw, tr_nb, w1_f, w2_f, w3_f, m_out);
  k_opm_ab<<<3072, 256, 0, stream>>>(m_out, opm_nw, opm_nb, opm_wa, opm_wb, at8, bt8);
  k_opm<<<4608, 512, 0, stream>>>(at8, bt8, wo8, opm_bo, z0, z1);
}

// Round 19
// 529.720 us; speedup vs baseline: 1.0053x; 1.0053x over previous
//
#include <hip/hip_runtime.h>
#include <hip/hip_bf16.h>

#define S_DIM 512
#define N_DIM 384
#define CM 64
#define CZ 128
#define HEADS 8
#define DH 32
#define HD 256

typedef __hip_bfloat16 bf16;
typedef long long i64;
typedef __attribute__((ext_vector_type(8))) short bf16x8;
typedef __attribute__((ext_vector_type(4))) float f32x4;

__device__ __forceinline__ float bf2f(bf16 x) { return __bfloat162float(x); }
__device__ __forceinline__ bf16 f2bf(float x) { return __float2bfloat16(x); }
__device__ __forceinline__ short f2bs(float x) {
  bf16 h = __float2bfloat16(x);
  return *reinterpret_cast<short*>(&h);
}

typedef __attribute__((address_space(3))) unsigned int lds_u32;
typedef __attribute__((address_space(1))) const unsigned int gbl_u32;
__device__ __forceinline__ void gl_lds16(const void* g, void* l) {
  __builtin_amdgcn_global_load_lds((gbl_u32*)g, (lds_u32*)l, 16, 0, 0);
}

// ---------------- weight prep: pack [K][N] fp32 -> bf16 MFMA B-fragments ----
// blocks 0..47: six m-path weights; block 48: wz fragment pack
__global__ __launch_bounds__(256) void k_wprep(const float* __restrict__ wm,
                                               const float* __restrict__ wg,
                                               const float* __restrict__ w1,
                                               const float* __restrict__ w2,
                                               const float* __restrict__ wpo,
                                               const float* __restrict__ w3,
                                               const float* __restrict__ wz,
                                               short* __restrict__ dst,
                                               short* __restrict__ wz_f) {
  if (blockIdx.x == 48) {
    int t = threadIdx.x;
    int ks = t >> 6, lane = t & 63, lg = lane >> 4, n = lane & 15;
    short out[8];
#pragma unroll
    for (int j = 0; j < 8; ++j) {
      int k = ks * 32 + lg * 8 + j;
      out[j] = (n < 8) ? f2bs(wz[k * 8 + n]) : (short)0;
    }
    *reinterpret_cast<float4*>(&wz_f[(size_t)t * 8]) =
        *reinterpret_cast<const float4*>(out);
    return;
  }
  int widx = blockIdx.x >> 3;
  const float* src;
  int N;
  if (widx == 0) { src = wm; N = 256; }
  else if (widx == 1) { src = wg; N = 256; }
  else if (widx == 2) { src = w1; N = 256; }
  else if (widx == 3) { src = w2; N = 256; }
  else if (widx == 4) { src = wpo; N = 64; }
  else { src = w3; N = 64; }
  int NF = N >> 4;
  int tg = ((blockIdx.x & 7) << 8) | threadIdx.x;
  int frag = tg >> 6, lane = tg & 63, lg = lane >> 4, l15 = lane & 15;
  int ks = frag / NF, nf = frag - ks * NF;
  short out[8];
#pragma unroll
  for (int j = 0; j < 8; ++j)
    out[j] = f2bs(src[(size_t)(ks * 32 + lg * 8 + j) * N + nf * 16 + l15]);
  *reinterpret_cast<float4*>(&dst[((size_t)widx << 14) + ((size_t)tg << 3)]) =
      *reinterpret_cast<const float4*>(out);
}

// ---------------- LN(z) + pair-bias logits via MFMA -------------------------
__global__ __launch_bounds__(256) void k_zb(const float* __restrict__ z,
                                            const float* __restrict__ w,
                                            const float* __restrict__ b,
                                            const short* __restrict__ wz_f,
                                            float* __restrict__ logits) {
  int blk = blockIdx.x;
  int i = blk / 6, j0 = (blk % 6) * 64;
  __shared__ __align__(16) char zl[16384];  // 64 rows x 256 B, swizzled bf16
  int t = threadIdx.x, wave = t >> 6, lane = t & 63;
  int lg = lane >> 4, l15 = lane & 15;
  float w0 = w[lane], w1 = w[lane + 64], b0 = b[lane], b1 = b[lane + 64];
  int rwb = wave * 16;
  const float* zbase = z + ((size_t)i * N_DIM + j0 + rwb) * CZ;
  for (int rr = 0; rr < 16; ++rr) {
    int row = rwb + rr;
    const float* zr = zbase + (size_t)rr * CZ;
    float v0 = zr[lane], v1 = zr[lane + 64];
    float s = v0 + v1, sq = v0 * v0 + v1 * v1;
#pragma unroll
    for (int off = 32; off; off >>= 1) {
      s += __shfl_xor(s, off);
      sq += __shfl_xor(sq, off);
    }
    float mu = s * (1.0f / CZ);
    float var = sq * (1.0f / CZ) - mu * mu;
    float rs = rsqrtf(var + 1e-5f);
    int sw = (row & 7) << 4;
    *reinterpret_cast<short*>(zl + row * 256 + ((2 * lane) ^ sw)) =
        f2bs((v0 - mu) * rs * w0 + b0);
    *reinterpret_cast<short*>(zl + row * 256 + ((2 * (lane + 64)) ^ sw)) =
        f2bs((v1 - mu) * rs * w1 + b1);
  }
  __syncthreads();
  f32x4 acc = (f32x4){0.f, 0.f, 0.f, 0.f};
  int arow = rwb + l15;
  int asw = (arow & 7) << 4;
#pragma unroll
  for (int ks = 0; ks < 4; ++ks) {
    bf16x8 a = *reinterpret_cast<const bf16x8*>(
        zl + arow * 256 + (((ks * 32 + lg * 8) * 2) ^ asw));
    bf16x8 bfr = *reinterpret_cast<const bf16x8*>(wz_f + ((size_t)ks * 64 + lane) * 8);
    acc = __builtin_amdgcn_mfma_f32_16x16x32_bf16(a, bfr, acc, 0, 0, 0);
  }
  if (l15 < 8) {
    int j = j0 + rwb + lg * 4;
    float4 o4;
    o4.x = acc[0]; o4.y = acc[1]; o4.z = acc[2]; o4.w = acc[3];
    *reinterpret_cast<float4*>(logits + ((size_t)i * 8 + l15) * N_DIM + j) = o4;
  }
}

// ---------------- softmax over j + direct bf16 emit to w8 [h][i][j] ---------
__global__ __launch_bounds__(128) void k_softmax(const float* __restrict__ wb,
                                                 short* __restrict__ w8) {
  int row = blockIdx.x;              // row = i*8 + h
  int i = row >> 3, h = row & 7;
  const float* p = wb + (size_t)row * N_DIM;
  int t = threadIdx.x;
  float a0 = p[t], a1 = p[t + 128], a2 = p[t + 256];
  float mx = fmaxf(a0, fmaxf(a1, a2));
  __shared__ float red[2], red2[2];
#pragma unroll
  for (int off = 32; off; off >>= 1) mx = fmaxf(mx, __shfl_xor(mx, off));
  if ((t & 63) == 0) red[t >> 6] = mx;
  __syncthreads();
  mx = fmaxf(red[0], red[1]);
  float e0 = __expf(a0 - mx), e1 = __expf(a1 - mx), e2 = __expf(a2 - mx);
  float s = e0 + e1 + e2;
#pragma unroll
  for (int off = 32; off; off >>= 1) s += __shfl_xor(s, off);
  if ((t & 63) == 0) red2[t >> 6] = s;
  __syncthreads();
  float inv = 1.0f / (red2[0] + red2[1]);
  short* wr = w8 + ((size_t)h * N_DIM + i) * N_DIM;
  wr[t] = f2bs(e0 * inv);
  wr[t + 128] = f2bs(e1 * inv);
  wr[t + 256] = f2bs(e2 * inv);
}

// ---------------- v = LN(m0) @ wm via MFMA (inline LN), emit vT[h][n][j] ----
__global__ __launch_bounds__(256, 1) void k_vgemm(const float* __restrict__ m0,
                                                  const float* __restrict__ nw,
                                                  const float* __restrict__ nb,
                                                  const short* __restrict__ wm_f,
                                                  short* __restrict__ vT) {
  int blk = blockIdx.x;
  int sblk = blk / 6, j0 = (blk % 6) * 64;
  __shared__ short vt[256 * 64];
  int t = threadIdx.x, wave = t >> 6, lane = t & 63;
  int lg = lane >> 4, l15 = lane & 15;
  size_t rb = (size_t)sblk * N_DIM + j0;
  int rw0 = wave * 16;
  const float* mrow = m0 + (rb + rw0 + l15) * CM;
  float4 x0 = *reinterpret_cast<const float4*>(mrow + lg * 8);
  float4 x1 = *reinterpret_cast<const float4*>(mrow + lg * 8 + 4);
  float4 x2 = *reinterpret_cast<const float4*>(mrow + 32 + lg * 8);
  float4 x3 = *reinterpret_cast<const float4*>(mrow + 32 + lg * 8 + 4);
  float s = x0.x + x0.y + x0.z + x0.w + x1.x + x1.y + x1.z + x1.w +
            x2.x + x2.y + x2.z + x2.w + x3.x + x3.y + x3.z + x3.w;
  float sq = x0.x * x0.x + x0.y * x0.y + x0.z * x0.z + x0.w * x0.w +
             x1.x * x1.x + x1.y * x1.y + x1.z * x1.z + x1.w * x1.w +
             x2.x * x2.x + x2.y * x2.y + x2.z * x2.z + x2.w * x2.w +
             x3.x * x3.x + x3.y * x3.y + x3.z * x3.z + x3.w * x3.w;
  s += __shfl_xor(s, 16); s += __shfl_xor(s, 32);
  sq += __shfl_xor(sq, 16); sq += __shfl_xor(sq, 32);
  float mu = s * (1.0f / CM);
  float var = sq * (1.0f / CM) - mu * mu;
  float rs = rsqrtf(var + 1e-5f);
  float4 g0 = *reinterpret_cast<const float4*>(nw + lg * 8);
  float4 g1 = *reinterpret_cast<const float4*>(nw + lg * 8 + 4);
  float4 g2 = *reinterpret_cast<const float4*>(nw + 32 + lg * 8);
  float4 g3 = *reinterpret_cast<const float4*>(nw + 32 + lg * 8 + 4);
  float4 c0 = *reinterpret_cast<const float4*>(nb + lg * 8);
  float4 c1 = *reinterpret_cast<const float4*>(nb + lg * 8 + 4);
  float4 c2 = *reinterpret_cast<const float4*>(nb + 32 + lg * 8);
  float4 c3 = *reinterpret_cast<const float4*>(nb + 32 + lg * 8 + 4);
  short av[16];
  av[0] = f2bs((x0.x - mu) * rs * g0.x + c0.x);
  av[1] = f2bs((x0.y - mu) * rs * g0.y + c0.y);
  av[2] = f2bs((x0.z - mu) * rs * g0.z + c0.z);
  av[3] = f2bs((x0.w - mu) * rs * g0.w + c0.w);
  av[4] = f2bs((x1.x - mu) * rs * g1.x + c1.x);
  av[5] = f2bs((x1.y - mu) * rs * g1.y + c1.y);
  av[6] = f2bs((x1.z - mu) * rs * g1.z + c1.z);
  av[7] = f2bs((x1.w - mu) * rs * g1.w + c1.w);
  av[8] = f2bs((x2.x - mu) * rs * g2.x + c2.x);
  av[9] = f2bs((x2.y - mu) * rs * g2.y + c2.y);
  av[10] = f2bs((x2.z - mu) * rs * g2.z + c2.z);
  av[11] = f2bs((x2.w - mu) * rs * g2.w + c2.w);
  av[12] = f2bs((x3.x - mu) * rs * g3.x + c3.x);
  av[13] = f2bs((x3.y - mu) * rs * g3.y + c3.y);
  av[14] = f2bs((x3.z - mu) * rs * g3.z + c3.z);
  av[15] = f2bs((x3.w - mu) * rs * g3.w + c3.w);
  bf16x8 a0 = *reinterpret_cast<const bf16x8*>(&av[0]);
  bf16x8 a1 = *reinterpret_cast<const bf16x8*>(&av[8]);
  f32x4 acc[16];
#pragma unroll
  for (int nf = 0; nf < 16; ++nf) acc[nf] = (f32x4){0.f, 0.f, 0.f, 0.f};
#pragma unroll
  for (int nf = 0; nf < 16; ++nf) {
    bf16x8 b0 = *reinterpret_cast<const bf16x8*>(wm_f + ((size_t)nf * 64 + lane) * 8);
    bf16x8 b1 = *reinterpret_cast<const bf16x8*>(wm_f + ((size_t)(16 + nf) * 64 + lane) * 8);
    acc[nf] = __builtin_amdgcn_mfma_f32_16x16x32_bf16(a0, b0, acc[nf], 0, 0, 0);
    acc[nf] = __builtin_amdgcn_mfma_f32_16x16x32_bf16(a1, b1, acc[nf], 0, 0, 0);
  }
#pragma unroll
  for (int nf = 0; nf < 16; ++nf)
#pragma unroll
    for (int r = 0; r < 4; ++r) {
      int jl = rw0 + lg * 4 + r;
      int hd = nf * 16 + l15;
      vt[hd * 64 + jl] = f2bs(acc[nf][r]);
    }
  __syncthreads();
  int h = t >> 5, d = t & 31;
  size_t gbase = ((size_t)h * 16384 + (size_t)sblk * 32 + d) * 384 + j0;
#pragma unroll
  for (int q = 0; q < 8; ++q)
    *reinterpret_cast<float4*>(&vT[gbase + q * 8]) =
        *reinterpret_cast<const float4*>(&vt[t * 64 + q * 8]);
}

// ---------------- o = W @ V per head, MFMA, dbuf prefetch (BJ=32) -----------
__global__ __launch_bounds__(256, 2) void k_ogemm(const short* __restrict__ w8,
                                                  const short* __restrict__ vT,
                                                  bf16* __restrict__ o) {
  int h = blockIdx.y;
  int u = blockIdx.x;
  int gid = (u & 7) * 24 + (u >> 3);   // bijective XCD chunking (192 = 8*24)
  int nb = gid / 3, ib = gid % 3;
  int i0 = ib * 128;
  __shared__ __align__(16) char lds8[49152];  // W: 2x8KB @0, V: 2x16KB @16384
  char* LW = lds8;
  char* LV = lds8 + 16384;
  int t = threadIdx.x, wave = t >> 6, lane = t & 63;
  int lg = lane >> 4, l15 = lane & 15;
  f32x4 acc[8][4];
#pragma unroll
  for (int a = 0; a < 8; ++a)
#pragma unroll
    for (int b = 0; b < 4; ++b) acc[a][b] = (f32x4){0.f, 0.f, 0.f, 0.f};
  const short* Wb = w8 + ((size_t)h * N_DIM + i0) * N_DIM;
  const short* Vb = vT + ((size_t)h * 16384 + (size_t)nb * 256) * N_DIM;

  auto STAGE = [&](int buf, int kt) {
    int j0 = kt * 32;
#pragma unroll
    for (int q = 0; q < 2; ++q) {
      int c = t + q * 256;
      int ri = c >> 2, s = c & 3;
      gl_lds16(Wb + (size_t)ri * N_DIM + j0 + ((s ^ (ri & 3)) << 3),
               LW + buf * 8192 + c * 16);
    }
#pragma unroll
    for (int q = 0; q < 4; ++q) {
      int c = t + q * 256;
      int rn = c >> 2, s = c & 3;
      gl_lds16(Vb + (size_t)rn * N_DIM + j0 + ((s ^ (rn & 3)) << 3),
               LV + buf * 16384 + c * 16);
    }
  };

  STAGE(0, 0);
  __syncthreads();
  for (int kt = 0; kt < 12; ++kt) {
    int cur = kt & 1;
    if (kt < 11) STAGE(cur ^ 1, kt + 1);
    bf16x8 bfr[4];
#pragma unroll
    for (int fn = 0; fn < 4; ++fn) {
      int nl = wave * 64 + fn * 16 + l15;
      bfr[fn] = *reinterpret_cast<const bf16x8*>(
          LV + cur * 16384 + nl * 64 + ((lg * 16) ^ ((nl & 3) << 4)));
    }
#pragma unroll
    for (int fm = 0; fm < 8; ++fm) {
      int il = fm * 16 + l15;
      bf16x8 af = *reinterpret_cast<const bf16x8*>(
          LW + cur * 8192 + il * 64 + ((lg * 16) ^ ((il & 3) << 4)));
#pragma unroll
      for (int fn = 0; fn < 4; ++fn)
        acc[fm][fn] = __builtin_amdgcn_mfma_f32_16x16x32_bf16(
            af, bfr[fn], acc[fm][fn], 0, 0, 0);
    }
    __syncthreads();
  }
#pragma unroll
  for (int fm = 0; fm < 8; ++fm)
#pragma unroll
    for (int fn = 0; fn < 4; ++fn)
#pragma unroll
      for (int r = 0; r < 4; ++r) {
        int i = i0 + fm * 16 + lg * 4 + r;
        int n = nb * 256 + wave * 64 + fn * 16 + l15;
        int s = n >> 5, d = n & 31;
        o[((size_t)s * N_DIM + i) * HD + h * DH + d] = f2bf(acc[fm][fn][r]);
      }
}

// ---------------- pwa out: inline LN; o staged via LDS; MFMA x2 -------------
#define OSTR 264
__global__ __launch_bounds__(256, 1) void k_pwa_out(const float* __restrict__ m0,
                                                    const bf16* __restrict__ o,
                                                    const float* __restrict__ nw,
                                                    const float* __restrict__ nb,
                                                    const short* __restrict__ wg_f,
                                                    const short* __restrict__ wpo_f,
                                                    float* __restrict__ m1out) {
  int blk = blockIdx.x;
  int sblk = blk / 6, j0 = (blk % 6) * 64;
  __shared__ __align__(16) short olds[64 * OSTR];   // 33,792 B (padded o tile)
  __shared__ __align__(16) char hlds[32768];
  int t = threadIdx.x, wave = t >> 6, lane = t & 63;
  int lg = lane >> 4, l15 = lane & 15;
  size_t rb0 = (size_t)sblk * N_DIM + j0;
  size_t rb = rb0 + wave * 16;
#pragma unroll
  for (int q = 0; q < 8; ++q) {
    int f = t + q * 256;
    int row = f >> 5, pos = f & 31;
    *reinterpret_cast<float4*>(&olds[row * OSTR + pos * 8]) =
        *reinterpret_cast<const float4*>((const short*)o + (rb0 + row) * HD + pos * 8);
  }
  const float* mrow = m0 + (rb + l15) * CM;
  float4 x0 = *reinterpret_cast<const float4*>(mrow + lg * 8);
  float4 x1 = *reinterpret_cast<const float4*>(mrow + lg * 8 + 4);
  float4 x2 = *reinterpret_cast<const float4*>(mrow + 32 + lg * 8);
  float4 x3 = *reinterpret_cast<const float4*>(mrow + 32 + lg * 8 + 4);
  float s = x0.x + x0.y + x0.z + x0.w + x1.x + x1.y + x1.z + x1.w +
            x2.x + x2.y + x2.z + x2.w + x3.x + x3.y + x3.z + x3.w;
  float sq = x0.x * x0.x + x0.y * x0.y + x0.z * x0.z + x0.w * x0.w +
             x1.x * x1.x + x1.y * x1.y + x1.z * x1.z + x1.w * x1.w +
             x2.x * x2.x + x2.y * x2.y + x2.z * x2.z + x2.w * x2.w +
             x3.x * x3.x + x3.y * x3.y + x3.z * x3.z + x3.w * x3.w;
  s += __shfl_xor(s, 16); s += __shfl_xor(s, 32);
  sq += __shfl_xor(sq, 16); sq += __shfl_xor(sq, 32);
  float mu = s * (1.0f / CM);
  float var = sq * (1.0f / CM) - mu * mu;
  float rs = rsqrtf(var + 1e-5f);
  float4 g0 = *reinterpret_cast<const float4*>(nw + lg * 8);
  float4 g1 = *reinterpret_cast<const float4*>(nw + lg * 8 + 4);
  float4 g2 = *reinterpret_cast<const float4*>(nw + 32 + lg * 8);
  float4 g3 = *reinterpret_cast<const float4*>(nw + 32 + lg * 8 + 4);
  float4 c0 = *reinterpret_cast<const float4*>(nb + lg * 8);
  float4 c1 = *reinterpret_cast<const float4*>(nb + lg * 8 + 4);
  float4 c2 = *reinterpret_cast<const float4*>(nb + 32 + lg * 8);
  float4 c3 = *reinterpret_cast<const float4*>(nb + 32 + lg * 8 + 4);
  short av[16];
  av[0] = f2bs((x0.x - mu) * rs * g0.x + c0.x);
  av[1] = f2bs((x0.y - mu) * rs * g0.y + c0.y);
  av[2] = f2bs((x0.z - mu) * rs * g0.z + c0.z);
  av[3] = f2bs((x0.w - mu) * rs * g0.w + c0.w);
  av[4] = f2bs((x1.x - mu) * rs * g1.x + c1.x);
  av[5] = f2bs((x1.y - mu) * rs * g1.y + c1.y);
  av[6] = f2bs((x1.z - mu) * rs * g1.z + c1.z);
  av[7] = f2bs((x1.w - mu) * rs * g1.w + c1.w);
  av[8] = f2bs((x2.x - mu) * rs * g2.x + c2.x);
  av[9] = f2bs((x2.y - mu) * rs * g2.y + c2.y);
  av[10] = f2bs((x2.z - mu) * rs * g2.z + c2.z);
  av[11] = f2bs((x2.w - mu) * rs * g2.w + c2.w);
  av[12] = f2bs((x3.x - mu) * rs * g3.x + c3.x);
  av[13] = f2bs((x3.y - mu) * rs * g3.y + c3.y);
  av[14] = f2bs((x3.z - mu) * rs * g3.z + c3.z);
  av[15] = f2bs((x3.w - mu) * rs * g3.w + c3.w);
  bf16x8 a0 = *reinterpret_cast<const bf16x8*>(&av[0]);
  bf16x8 a1 = *reinterpret_cast<const bf16x8*>(&av[8]);
  f32x4 acc[16];
#pragma unroll
  for (int nf = 0; nf < 16; ++nf) acc[nf] = (f32x4){0.f, 0.f, 0.f, 0.f};
#pragma unroll
  for (int nf = 0; nf < 16; ++nf) {
    bf16x8 b0 = *reinterpret_cast<const bf16x8*>(wg_f + ((size_t)nf * 64 + lane) * 8);
    bf16x8 b1 = *reinterpret_cast<const bf16x8*>(wg_f + ((size_t)(16 + nf) * 64 + lane) * 8);
    acc[nf] = __builtin_amdgcn_mfma_f32_16x16x32_bf16(a0, b0, acc[nf], 0, 0, 0);
    acc[nf] = __builtin_amdgcn_mfma_f32_16x16x32_bf16(a1, b1, acc[nf], 0, 0, 0);
  }
  __syncthreads();  // olds staged (all waves), safe to read
  char* hb = hlds + wave * 8192;
#pragma unroll
  for (int nf = 0; nf < 16; ++nf)
#pragma unroll
    for (int r = 0; r < 4; ++r) {
      int row = lg * 4 + r;
      float x = acc[nf][r];
      float g = 1.0f / (1.0f + __expf(-x));
      float ov = bf2f(*reinterpret_cast<const bf16*>(
          &olds[(wave * 16 + row) * OSTR + nf * 16 + l15]));
      *reinterpret_cast<short*>(
          hb + row * 512 + (((nf * 16 + l15) * 2) ^ ((row & 7) << 4))) = f2bs(g * ov);
    }
  __syncthreads();
  f32x4 acc3[4];
#pragma unroll
  for (int nf2 = 0; nf2 < 4; ++nf2) acc3[nf2] = (f32x4){0.f, 0.f, 0.f, 0.f};
#pragma unroll
  for (int ks2 = 0; ks2 < 8; ++ks2) {
    bf16x8 a2 = *reinterpret_cast<const bf16x8*>(
        hb + l15 * 512 + ((ks2 * 64 + lg * 16) ^ ((l15 & 7) << 4)));
#pragma unroll
    for (int nf2 = 0; nf2 < 4; ++nf2) {
      bf16x8 b = *reinterpret_cast<const bf16x8*>(
          wpo_f + ((size_t)(ks2 * 4 + nf2) * 64 + lane) * 8);
      acc3[nf2] = __builtin_amdgcn_mfma_f32_16x16x32_bf16(a2, b, acc3[nf2], 0, 0, 0);
    }
  }
#pragma unroll
  for (int nf2 = 0; nf2 < 4; ++nf2)
#pragma unroll
    for (int r = 0; r < 4; ++r) {
      size_t a = (rb + lg * 4 + r) * CM + nf2 * 16 + l15;
      m1out[a] = m0[a] + acc3[nf2][r];
    }
}

// ---------------- transition via MFMA: m2 = m1 + (silu(tn@w1)*(tn@w2))@w3 ---
__global__ __launch_bounds__(256, 1) void k_transition(const float* __restrict__ nw,
                                                       const float* __restrict__ nb,
                                                       const short* __restrict__ w1_f,
                                                       const short* __restrict__ w2_f,
                                                       const short* __restrict__ w3_f,
                                                       float* __restrict__ mio) {
  __shared__ __align__(16) char hlds[32768];
  int t = threadIdx.x, wave = t >> 6, lane = t & 63;
  int lg = lane >> 4, l15 = lane & 15;
  size_t rb = (size_t)blockIdx.x * 64 + wave * 16;
  const float* mrow = mio + (rb + l15) * CM;
  float4 x0 = *reinterpret_cast<const float4*>(mrow + lg * 8);
  float4 x1 = *reinterpret_cast<const float4*>(mrow + lg * 8 + 4);
  float4 x2 = *reinterpret_cast<const float4*>(mrow + 32 + lg * 8);
  float4 x3 = *reinterpret_cast<const float4*>(mrow + 32 + lg * 8 + 4);
  float s = x0.x + x0.y + x0.z + x0.w + x1.x + x1.y + x1.z + x1.w +
            x2.x + x2.y + x2.z + x2.w + x3.x + x3.y + x3.z + x3.w;
  float sq = x0.x * x0.x + x0.y * x0.y + x0.z * x0.z + x0.w * x0.w +
             x1.x * x1.x + x1.y * x1.y + x1.z * x1.z + x1.w * x1.w +
             x2.x * x2.x + x2.y * x2.y + x2.z * x2.z + x2.w * x2.w +
             x3.x * x3.x + x3.y * x3.y + x3.z * x3.z + x3.w * x3.w;
  s += __shfl_xor(s, 16); s += __shfl_xor(s, 32);
  sq += __shfl_xor(sq, 16); sq += __shfl_xor(sq, 32);
  float mu = s * (1.0f / CM);
  float var = sq * (1.0f / CM) - mu * mu;
  float rs = rsqrtf(var + 1e-5f);
  float4 g0 = *reinterpret_cast<const float4*>(nw + lg * 8);
  float4 g1 = *reinterpret_cast<const float4*>(nw + lg * 8 + 4);
  float4 g2 = *reinterpret_cast<const float4*>(nw + 32 + lg * 8);
  float4 g3 = *reinterpret_cast<const float4*>(nw + 32 + lg * 8 + 4);
  float4 c0 = *reinterpret_cast<const float4*>(nb + lg * 8);
  float4 c1 = *reinterpret_cast<const float4*>(nb + lg * 8 + 4);
  float4 c2 = *reinterpret_cast<const float4*>(nb + 32 + lg * 8);
  float4 c3 = *reinterpret_cast<const float4*>(nb + 32 + lg * 8 + 4);
  short av[16];
  av[0] = f2bs((x0.x - mu) * rs * g0.x + c0.x);
  av[1] = f2bs((x0.y - mu) * rs * g0.y + c0.y);
  av[2] = f2bs((x0.z - mu) * rs * g0.z + c0.z);
  av[3] = f2bs((x0.w - mu) * rs * g0.w + c0.w);
  av[4] = f2bs((x1.x - mu) * rs * g1.x + c1.x);
  av[5] = f2bs((x1.y - mu) * rs * g1.y + c1.y);
  av[6] = f2bs((x1.z - mu) * rs * g1.z + c1.z);
  av[7] = f2bs((x1.w - mu) * rs * g1.w + c1.w);
  av[8] = f2bs((x2.x - mu) * rs * g2.x + c2.x);
  av[9] = f2bs((x2.y - mu) * rs * g2.y + c2.y);
  av[10] = f2bs((x2.z - mu) * rs * g2.z + c2.z);
  av[11] = f2bs((x2.w - mu) * rs * g2.w + c2.w);
  av[12] = f2bs((x3.x - mu) * rs * g3.x + c3.x);
  av[13] = f2bs((x3.y - mu) * rs * g3.y + c3.y);
  av[14] = f2bs((x3.z - mu) * rs * g3.z + c3.z);
  av[15] = f2bs((x3.w - mu) * rs * g3.w + c3.w);
  bf16x8 a0 = *reinterpret_cast<const bf16x8*>(&av[0]);
  bf16x8 a1 = *reinterpret_cast<const bf16x8*>(&av[8]);
  f32x4 acc1[16], acc2[16];
#pragma unroll
  for (int nf = 0; nf < 16; ++nf) {
    acc1[nf] = (f32x4){0.f, 0.f, 0.f, 0.f};
    acc2[nf] = (f32x4){0.f, 0.f, 0.f, 0.f};
  }
#pragma unroll
  for (int nf = 0; nf < 16; ++nf) {
    bf16x8 b10 = *reinterpret_cast<const bf16x8*>(w1_f + ((size_t)nf * 64 + lane) * 8);
    bf16x8 b11 = *reinterpret_cast<const bf16x8*>(w1_f + ((size_t)(16 + nf) * 64 + lane) * 8);
    acc1[nf] = __builtin_amdgcn_mfma_f32_16x16x32_bf16(a0, b10, acc1[nf], 0, 0, 0);
    acc1[nf] = __builtin_amdgcn_mfma_f32_16x16x32_bf16(a1, b11, acc1[nf], 0, 0, 0);
    bf16x8 b20 = *reinterpret_cast<const bf16x8*>(w2_f + ((size_t)nf * 64 + lane) * 8);
    bf16x8 b21 = *reinterpret_cast<const bf16x8*>(w2_f + ((size_t)(16 + nf) * 64 + lane) * 8);
    acc2[nf] = __builtin_amdgcn_mfma_f32_16x16x32_bf16(a0, b20, acc2[nf], 0, 0, 0);
    acc2[nf] = __builtin_amdgcn_mfma_f32_16x16x32_bf16(a1, b21, acc2[nf], 0, 0, 0);
  }
  char* hb = hlds + wave * 8192;
#pragma unroll
  for (int nf = 0; nf < 16; ++nf)
#pragma unroll
    for (int r = 0; r < 4; ++r) {
      int row = lg * 4 + r;
      float x = acc1[nf][r];
      float h = (x / (1.0f + __expf(-x))) * acc2[nf][r];
      *reinterpret_cast<short*>(
          hb + row * 512 + (((nf * 16 + l15) * 2) ^ ((row & 7) << 4))) = f2bs(h);
    }
  __syncthreads();
  f32x4 acc3[4];
#pragma unroll
  for (int nf2 = 0; nf2 < 4; ++nf2) acc3[nf2] = (f32x4){0.f, 0.f, 0.f, 0.f};
#pragma unroll
  for (int ks2 = 0; ks2 < 8; ++ks2) {
    bf16x8 a2 = *reinterpret_cast<const bf16x8*>(
        hb + l15 * 512 + ((ks2 * 64 + lg * 16) ^ ((l15 & 7) << 4)));
#pragma unroll
    for (int nf2 = 0; nf2 < 4; ++nf2) {
      bf16x8 b = *reinterpret_cast<const bf16x8*>(
          w3_f + ((size_t)(ks2 * 4 + nf2) * 64 + lane) * 8);
      acc3[nf2] = __builtin_amdgcn_mfma_f32_16x16x32_bf16(a2, b, acc3[nf2], 0, 0, 0);
    }
  }
#pragma unroll
  for (int nf2 = 0; nf2 < 4; ++nf2)
#pragma unroll
    for (int r = 0; r < 4; ++r) {
      size_t a = (rb + lg * 4 + r) * CM + nf2 * 16 + l15;
      mio[a] = mio[a] + acc3[nf2][r];
    }
}

// ---------------- opm a/b: LN(m2)@wa/wb -> fp8 e4m3, FRAGMENT-PACKED --------
__global__ __launch_bounds__(256) void k_opm_ab(const float* __restrict__ m2,
                                                const float* __restrict__ nw,
                                                const float* __restrict__ nb,
                                                const float* __restrict__ wa,
                                                const float* __restrict__ wb,
                                                unsigned char* __restrict__ at8,
                                                unsigned char* __restrict__ bt8) {
  int bix = blockIdx.x;
  int sg = bix / N_DIM;
  int i = bix - sg * N_DIM;
  __shared__ float on[64][65];
  __shared__ float wl[2][64][36];
  __shared__ float tl[2][32][65];
  int t = threadIdx.x, w = t >> 6, lane = t & 63;
  float gw = nw[lane], gb = nb[lane];
  for (int rr = 0; rr < 16; ++rr) {
    int sl = w * 16 + rr;
    float x = m2[((size_t)(sg * 64 + sl) * N_DIM + i) * CM + lane];
    float s = x, sq = x * x;
#pragma unroll
    for (int off = 32; off; off >>= 1) {
      s += __shfl_xor(s, off);
      sq += __shfl_xor(sq, off);
    }
    float mu = s * (1.0f / CM);
    float var = sq * (1.0f / CM) - mu * mu;
    float rs = rsqrtf(var + 1e-5f);
    on[sl][lane] = (x - mu) * rs * gw + gb;
  }
  for (int idx = t; idx < 2048; idx += 256) {
    int k = idx >> 5, c = idx & 31;
    wl[0][k][c] = wa[idx];
    wl[1][k][c] = wb[idx];
  }
  __syncthreads();
  int s = t >> 2, c0 = (t & 3) * 8;
  float accA[8], accB[8];
#pragma unroll
  for (int j = 0; j < 8; ++j) { accA[j] = 0.0f; accB[j] = 0.0f; }
  for (int k = 0; k < 64; ++k) {
    float ov = on[s][k];
#pragma unroll
    for (int j = 0; j < 8; ++j) {
      accA[j] += ov * wl[0][k][c0 + j];
      accB[j] += ov * wl[1][k][c0 + j];
    }
  }
#pragma unroll
  for (int j = 0; j < 8; ++j) {
    tl[0][c0 + j][s] = accA[j];
    tl[1][c0 + j][s] = accB[j];
  }
  __syncthreads();
  int cc = t >> 3, s8 = (t & 7) * 8;
  int lane8 = ((((s8 & 31) >> 3) * 16) + (cc & 15)) * 8;
  int kg = sg * 2 + (s8 >> 5);
  size_t obA = (size_t)(i >> 3) * 131072 + (size_t)kg * 8192 +
               (size_t)((i & 7) * 2 + (cc >> 4)) * 512 + lane8;
  size_t obB = (size_t)(i >> 2) * 65536 + (size_t)kg * 4096 +
               (size_t)((i & 3) * 2 + (cc >> 4)) * 512 + lane8;
  unsigned int p0 = 0, p1 = 0;
  p0 = __builtin_amdgcn_cvt_pk_fp8_f32(tl[0][cc][s8 + 0], tl[0][cc][s8 + 1], p0, false);
  p0 = __builtin_amdgcn_cvt_pk_fp8_f32(tl[0][cc][s8 + 2], tl[0][cc][s8 + 3], p0, true);
  p1 = __builtin_amdgcn_cvt_pk_fp8_f32(tl[0][cc][s8 + 4], tl[0][cc][s8 + 5], p1, false);
  p1 = __builtin_amdgcn_cvt_pk_fp8_f32(tl[0][cc][s8 + 6], tl[0][cc][s8 + 7], p1, true);
  uint2 pa = {p0, p1};
  *reinterpret_cast<uint2*>(at8 + obA) = pa;
  p0 = 0; p1 = 0;
  p0 = __builtin_amdgcn_cvt_pk_fp8_f32(tl[1][cc][s8 + 0], tl[1][cc][s8 + 1], p0, false);
  p0 = __builtin_amdgcn_cvt_pk_fp8_f32(tl[1][cc][s8 + 2], tl[1][cc][s8 + 3], p0, true);
  p1 = __builtin_amdgcn_cvt_pk_fp8_f32(tl[1][cc][s8 + 4], tl[1][cc][s8 + 5], p1, false);
  p1 = __builtin_amdgcn_cvt_pk_fp8_f32(tl[1][cc][s8 + 6], tl[1][cc][s8 + 7], p1, true);
  uint2 pb = {p0, p1};
  *reinterpret_cast<uint2*>(bt8 + obB) = pb;
}

// ---------------- wo8: fragment-packed wo (fp8 e4m3), permuted k=(d<<5)|c ---
__global__ __launch_bounds__(256) void k_wot(const float* __restrict__ wo,
                                             unsigned char* __restrict__ wo8) {
  int tg = blockIdx.x * 256 + threadIdx.x;   // 64 blocks -> 16384 fragments
  int frag = tg >> 6, lane = tg & 63;
  int eblk = frag >> 5, kc = frag & 31;
  int e = eblk * 16 + (lane & 15);
  int kbase = kc * 32 + (lane >> 4) * 8;
  float v[8];
#pragma unroll
  for (int j = 0; j < 8; ++j) {
    int q = kbase + j;                       // permuted index cd2 = (d<<5)|c
    int row = ((q & 31) << 5) | (q >> 5);    // original wo row = c*32 + d
    v[j] = wo[(size_t)row * CZ + e];
  }
  unsigned int p0 = 0, p1 = 0;
  p0 = __builtin_amdgcn_cvt_pk_fp8_f32(v[0], v[1], p0, false);
  p0 = __builtin_amdgcn_cvt_pk_fp8_f32(v[2], v[3], p0, true);
  p1 = __builtin_amdgcn_cvt_pk_fp8_f32(v[4], v[5], p1, false);
  p1 = __builtin_amdgcn_cvt_pk_fp8_f32(v[6], v[7], p1, true);
  uint2 pk = {p0, p1};
  *reinterpret_cast<uint2*>(wo8 + (size_t)tg * 8) = pk;
}

// ---------------- OPM: fp8 MFMA 256x128, fragment LDS, fp8 P epilogue -------
#define PS 1064   // P row stride bytes (266 dwords; gcd(266,32)=2 -> ~free)
__global__ __launch_bounds__(512, 2) void k_opm(const unsigned char* __restrict__ at8,
                                                const unsigned char* __restrict__ bt8,
                                                const unsigned char* __restrict__ wo8,
                                                const float* __restrict__ bo,
                                                const float* __restrict__ z0,
                                                float* __restrict__ z1) {
  // XCD mapping: xcd owns bm in [xcd*6, xcd*6+6), traversal bn-outer (4608=8*576)
  int g = blockIdx.x;
  int xcd = g & 7, u = g >> 3;
  int bn = u / 6;
  int bm = xcd * 6 + (u - bn * 6);
  // A: 2x16KB @0, B: 2x8KB @32768; P fp8 (32 x 1064 = 34048 B) overlays
  __shared__ __align__(16) char lds8[49152];
  char* LA = lds8;
  char* LB = lds8 + 32768;
  int t = threadIdx.x, wave = t >> 6, lane = t & 63;
  int wm2 = wave >> 1, wn2 = wave & 1;   // 4m x 2n wave grid, 64x64 tiles
  int lg = lane >> 4, l15 = lane & 15;
  f32x4 acc[4][4];
#pragma unroll
  for (int a = 0; a < 4; ++a)
#pragma unroll
    for (int b = 0; b < 4; ++b) acc[a][b] = (f32x4){0.f, 0.f, 0.f, 0.f};
  const unsigned char* A = at8 + (size_t)bm * 131072;   // [kg16][mg16][512]
  const unsigned char* B = bt8 + (size_t)bn * 65536;    // [kg16][ng8][512]

  auto STAGE = [&](int buf, int kt) {
    gl_lds16(A + (size_t)kt * 16384 + t * 16, LA + buf * 16384 + t * 16);
    gl_lds16(A + (size_t)kt * 16384 + 8192 + t * 16,
             LA + buf * 16384 + 8192 + t * 16);
    gl_lds16(B + (size_t)kt * 8192 + t * 16, LB + buf * 8192 + t * 16);
  };

  STAGE(0, 0);
  __syncthreads();
  for (int kt = 0; kt < 8; ++kt) {
    int cur = kt & 1;
    if (kt < 7) STAGE(cur ^ 1, kt + 1);
    const char* LAc = LA + cur * 16384;
    const char* LBc = LB + cur * 8192;
#pragma unroll
    for (int ks = 0; ks < 2; ++ks) {
      i64 bfr[4];
#pragma unroll
      for (int fn = 0; fn < 4; ++fn)
        bfr[fn] = *reinterpret_cast<const i64*>(
            LBc + ks * 4096 + (wn2 * 4 + fn) * 512 + lane * 8);
#pragma unroll
      for (int fm = 0; fm < 4; ++fm) {
        i64 af = *reinterpret_cast<const i64*>(
            LAc + ks * 8192 + (wm2 * 4 + fm) * 512 + lane * 8);
#pragma unroll
        for (int fn = 0; fn < 4; ++fn)
          acc[fm][fn] = __builtin_amdgcn_mfma_f32_16x16x32_fp8_fp8(
              af, bfr[fn], acc[fm][fn], 0, 0, 0);
      }
    }
    __syncthreads();
  }

  // --- one-shot P write (fp8, scaled x1024/512=2): P[32 pairs][PS bytes] ---
  unsigned char* P = (unsigned char*)lds8;
  const float sc = 2.0f;          // op*1024 when combined with 1/512
#pragma unroll
  for (int fm = 0; fm < 4; ++fm)
#pragma unroll
    for (int fn = 0; fn < 4; ++fn) {
      int m = wm2 * 64 + fm * 16 + lg * 4;   // 4 consecutive m (r)
      int n = wn2 * 64 + fn * 16 + l15;
      int prow = (m >> 5) * 4 + (n >> 5);
      int cd2 = ((n & 31) << 5) | (m & 31);
      unsigned int p0 = 0;
      p0 = __builtin_amdgcn_cvt_pk_fp8_f32(acc[fm][fn][0] * sc,
                                           acc[fm][fn][1] * sc, p0, false);
      p0 = __builtin_amdgcn_cvt_pk_fp8_f32(acc[fm][fn][2] * sc,
                                           acc[fm][fn][3] * sc, p0, true);
      *reinterpret_cast<unsigned int*>(P + prow * PS + cd2) = p0;
    }
  __syncthreads();

  // --- projection (fp8 x fp8): 2 pair-groups x 8 e-blocks, 8 waves ---
  int eblk = wave;
#pragma unroll
  for (int it = 0; it < 2; ++it) {
    f32x4 pacc = (f32x4){0.f, 0.f, 0.f, 0.f};
    for (int c0 = 0; c0 < 1024; c0 += 32) {
      i64 pa = *reinterpret_cast<const i64*>(
          P + (it * 16 + l15) * PS + c0 + lg * 8);
      i64 pb = *reinterpret_cast<const i64*>(
          wo8 + ((size_t)(eblk * 32 + (c0 >> 5)) * 64 + lane) * 8);
      pacc = __builtin_amdgcn_mfma_f32_16x16x32_fp8_fp8(pa, pb, pacc, 0, 0, 0);
    }
    int e = eblk * 16 + l15;
    float bov = bo[e];
#pragma unroll
    for (int r = 0; r < 4; ++r) {
      int prow = it * 16 + lg * 4 + r;
      int gi = bm * 8 + (prow >> 2), gj = bn * 4 + (prow & 3);
      size_t addr = ((size_t)gi * N_DIM + gj) * CZ + e;
      z1[addr] = z0[addr] + pacc[r] * (1.0f / 1024.0f) + bov;
    }
  }
}

// ---------------------------------------------------------------------------
extern "C" void kernel_launch(void* const* d_in, const int* in_sizes, int n_in,
                              void* d_out, int out_size, void* d_ws, size_t ws_size,
                              hipStream_t stream) {
  const float* m0 = (const float*)d_in[0];
  const float* z0 = (const float*)d_in[1];
  const float* pwa_nm_w = (const float*)d_in[2];
  const float* pwa_nm_b = (const float*)d_in[3];
  const float* pwa_nz_w = (const float*)d_in[4];
  const float* pwa_nz_b = (const float*)d_in[5];
  const float* pwa_wm = (const float*)d_in[6];
  const float* pwa_wg = (const float*)d_in[7];
  const float* pwa_wz = (const float*)d_in[8];
  const float* pwa_wo = (const float*)d_in[9];
  const float* tr_nw = (const float*)d_in[10];
  const float* tr_nb = (const float*)d_in[11];
  const float* tr_w1 = (const float*)d_in[12];
  const float* tr_w2 = (const float*)d_in[13];
  const float* tr_w3 = (const float*)d_in[14];
  const float* opm_nw = (const float*)d_in[15];
  const float* opm_nb = (const float*)d_in[16];
  const float* opm_wa = (const float*)d_in[17];
  const float* opm_wb = (const float*)d_in[18];
  const float* opm_wo = (const float*)d_in[19];
  const float* opm_bo = (const float*)d_in[20];

  char* ws = (char*)d_ws;
  float* wbuf = (float*)(ws + 25165824);         //  4,718,592 B
  short* vT = (short*)(ws + 29884416);           // 100,663,296 B
  bf16* o = (bf16*)(ws + 130547712);             // 100,663,296 B
  // reuse dead vT region after k_ogemm:
  unsigned char* at8 = (unsigned char*)(ws + 29884416);  // 6,291,456 B
  unsigned char* bt8 = at8 + 6291456;                    // 6,291,456 B
  unsigned char* wo8 = (unsigned char*)(ws + 55050240);  //   131,072 B
  short* wz_f = (short*)(ws + 55312384);                 //     4,096 B

  float* m_out = (float*)d_out;
  float* z1 = m_out + (size_t)S_DIM * N_DIM * CM;
  // scratch in the z1 region of d_out (dead until k_opm overwrites all of z1)
  short* packW = (short*)z1;                     // 6 x 32 KB
  short* wm_f = packW;
  short* wg_f = packW + 16384;
  short* w1_f = packW + 32768;
  short* w2_f = packW + 49152;
  short* wpo_f = packW + 65536;
  short* w3_f = packW + 81920;
  short* w8 = (short*)((char*)z1 + 262144);      // 2,359,296 B (bf16 softmax W)

  k_wprep<<<49, 256, 0, stream>>>(pwa_wm, pwa_wg, tr_w1, tr_w2, pwa_wo, tr_w3,
                                  pwa_wz, packW, wz_f);
  k_zb<<<2304, 256, 0, stream>>>(z0, pwa_nz_w, pwa_nz_b, wz_f, wbuf);
  k_softmax<<<3072, 128, 0, stream>>>(wbuf, w8);
  k_vgemm<<<3072, 256, 0, stream>>>(m0, pwa_nm_w, pwa_nm_b, wm_f, vT);
  k_ogemm<<<dim3(192, 8), 256, 0, stream>>>(w8, vT, o);
  k_pwa_out<<<3072, 256, 0, stream>>>(m0, o, pwa_nm_w, pwa_nm_b, wg_f, wpo_f, m_out);
  k_wot<<<64, 256, 0, stream>>>(opm_wo, wo8);
  k_transition<<<3072, 256, 0, stream>>>(tr_nw, tr_nb, w1_f, w2_f, w3_f, m_out);
  k_opm_ab<<<3072, 256, 0, stream>>>(m_out, opm_nw, opm_nb, opm_wa, opm_wb, at8, bt8);
  k_opm<<<4608, 512, 0, stream>>>(at8, bt8, wo8, opm_bo, z0, z1);
}

// Round 20
// 522.886 us; speedup vs baseline: 1.0184x; 1.0131x over previous
//
#include <hip/hip_runtime.h>
#include <hip/hip_bf16.h>

#define S_DIM 512
#define N_DIM 384
#define CM 64
#define CZ 128
#define HEADS 8
#define DH 32
#define HD 256

typedef __hip_bfloat16 bf16;
typedef long long i64;
typedef __attribute__((ext_vector_type(8))) short bf16x8;
typedef __attribute__((ext_vector_type(4))) float f32x4;

__device__ __forceinline__ float bf2f(bf16 x) { return __bfloat162float(x); }
__device__ __forceinline__ bf16 f2bf(float x) { return __float2bfloat16(x); }
__device__ __forceinline__ short f2bs(float x) {
  bf16 h = __float2bfloat16(x);
  return *reinterpret_cast<short*>(&h);
}

typedef __attribute__((address_space(3))) unsigned int lds_u32;
typedef __attribute__((address_space(1))) const unsigned int gbl_u32;
__device__ __forceinline__ void gl_lds16(const void* g, void* l) {
  __builtin_amdgcn_global_load_lds((gbl_u32*)g, (lds_u32*)l, 16, 0, 0);
}

// ---------------- weight prep: pack [K][N] fp32 -> bf16 MFMA B-fragments ----
// blocks 0..47: six m-path weights; block 48: wz fragment pack
__global__ __launch_bounds__(256) void k_wprep(const float* __restrict__ wm,
                                               const float* __restrict__ wg,
                                               const float* __restrict__ w1,
                                               const float* __restrict__ w2,
                                               const float* __restrict__ wpo,
                                               const float* __restrict__ w3,
                                               const float* __restrict__ wz,
                                               short* __restrict__ dst,
                                               short* __restrict__ wz_f) {
  if (blockIdx.x == 48) {
    int t = threadIdx.x;
    int ks = t >> 6, lane = t & 63, lg = lane >> 4, n = lane & 15;
    short out[8];
#pragma unroll
    for (int j = 0; j < 8; ++j) {
      int k = ks * 32 + lg * 8 + j;
      out[j] = (n < 8) ? f2bs(wz[k * 8 + n]) : (short)0;
    }
    *reinterpret_cast<float4*>(&wz_f[(size_t)t * 8]) =
        *reinterpret_cast<const float4*>(out);
    return;
  }
  int widx = blockIdx.x >> 3;
  const float* src;
  int N;
  if (widx == 0) { src = wm; N = 256; }
  else if (widx == 1) { src = wg; N = 256; }
  else if (widx == 2) { src = w1; N = 256; }
  else if (widx == 3) { src = w2; N = 256; }
  else if (widx == 4) { src = wpo; N = 64; }
  else { src = w3; N = 64; }
  int NF = N >> 4;
  int tg = ((blockIdx.x & 7) << 8) | threadIdx.x;
  int frag = tg >> 6, lane = tg & 63, lg = lane >> 4, l15 = lane & 15;
  int ks = frag / NF, nf = frag - ks * NF;
  short out[8];
#pragma unroll
  for (int j = 0; j < 8; ++j)
    out[j] = f2bs(src[(size_t)(ks * 32 + lg * 8 + j) * N + nf * 16 + l15]);
  *reinterpret_cast<float4*>(&dst[((size_t)widx << 14) + ((size_t)tg << 3)]) =
      *reinterpret_cast<const float4*>(out);
}

// ---------------- LN(z) + pair-bias logits via MFMA -------------------------
// parallel-row LN: lane (lg,l15) owns 32 floats of row rwb+l15; 2 shfl/group
__global__ __launch_bounds__(256) void k_zb(const float* __restrict__ z,
                                            const float* __restrict__ w,
                                            const float* __restrict__ b,
                                            const short* __restrict__ wz_f,
                                            float* __restrict__ logits) {
  int blk = blockIdx.x;
  int i = blk / 6, j0 = (blk % 6) * 64;
  __shared__ __align__(16) char zl[16384];  // 64 rows x 256 B, swizzled bf16
  int t = threadIdx.x, wave = t >> 6, lane = t & 63;
  int lg = lane >> 4, l15 = lane & 15;
  int rwb = wave * 16;
  int row = rwb + l15;
  const float* zr = z + ((size_t)i * N_DIM + j0 + row) * CZ + lg * 32;
  float4 xv[8];
#pragma unroll
  for (int q = 0; q < 8; ++q)
    xv[q] = *reinterpret_cast<const float4*>(zr + q * 4);
  float s = 0.f, sq = 0.f;
#pragma unroll
  for (int q = 0; q < 8; ++q) {
    s += xv[q].x + xv[q].y + xv[q].z + xv[q].w;
    sq += xv[q].x * xv[q].x + xv[q].y * xv[q].y +
          xv[q].z * xv[q].z + xv[q].w * xv[q].w;
  }
  s += __shfl_xor(s, 16); s += __shfl_xor(s, 32);
  sq += __shfl_xor(sq, 16); sq += __shfl_xor(sq, 32);
  float mu = s * (1.0f / CZ);
  float var = sq * (1.0f / CZ) - mu * mu;
  float rs = rsqrtf(var + 1e-5f);
  int sw = (row & 7) << 4;
  char* zrow = zl + row * 256;
#pragma unroll
  for (int q = 0; q < 8; ++q) {
    int col = lg * 32 + q * 4;
    float4 wv = *reinterpret_cast<const float4*>(w + col);
    float4 bv = *reinterpret_cast<const float4*>(b + col);
    short o4[4];
    o4[0] = f2bs((xv[q].x - mu) * rs * wv.x + bv.x);
    o4[1] = f2bs((xv[q].y - mu) * rs * wv.y + bv.y);
    o4[2] = f2bs((xv[q].z - mu) * rs * wv.z + bv.z);
    o4[3] = f2bs((xv[q].w - mu) * rs * wv.w + bv.w);
    *reinterpret_cast<i64*>(zrow + ((2 * col) ^ sw)) =
        *reinterpret_cast<const i64*>(o4);
  }
  __syncthreads();
  f32x4 acc = (f32x4){0.f, 0.f, 0.f, 0.f};
  int arow = rwb + l15;
  int asw = (arow & 7) << 4;
#pragma unroll
  for (int ks = 0; ks < 4; ++ks) {
    bf16x8 a = *reinterpret_cast<const bf16x8*>(
        zl + arow * 256 + (((ks * 32 + lg * 8) * 2) ^ asw));
    bf16x8 bfr = *reinterpret_cast<const bf16x8*>(wz_f + ((size_t)ks * 64 + lane) * 8);
    acc = __builtin_amdgcn_mfma_f32_16x16x32_bf16(a, bfr, acc, 0, 0, 0);
  }
  if (l15 < 8) {
    int j = j0 + rwb + lg * 4;
    float4 o4;
    o4.x = acc[0]; o4.y = acc[1]; o4.z = acc[2]; o4.w = acc[3];
    *reinterpret_cast<float4*>(logits + ((size_t)i * 8 + l15) * N_DIM + j) = o4;
  }
}

// ---------------- softmax over j + direct bf16 emit to w8 [h][i][j] ---------
__global__ __launch_bounds__(128) void k_softmax(const float* __restrict__ wb,
                                                 short* __restrict__ w8) {
  int row = blockIdx.x;              // row = i*8 + h
  int i = row >> 3, h = row & 7;
  const float* p = wb + (size_t)row * N_DIM;
  int t = threadIdx.x;
  float a0 = p[t], a1 = p[t + 128], a2 = p[t + 256];
  float mx = fmaxf(a0, fmaxf(a1, a2));
  __shared__ float red[2], red2[2];
#pragma unroll
  for (int off = 32; off; off >>= 1) mx = fmaxf(mx, __shfl_xor(mx, off));
  if ((t & 63) == 0) red[t >> 6] = mx;
  __syncthreads();
  mx = fmaxf(red[0], red[1]);
  float e0 = __expf(a0 - mx), e1 = __expf(a1 - mx), e2 = __expf(a2 - mx);
  float s = e0 + e1 + e2;
#pragma unroll
  for (int off = 32; off; off >>= 1) s += __shfl_xor(s, off);
  if ((t & 63) == 0) red2[t >> 6] = s;
  __syncthreads();
  float inv = 1.0f / (red2[0] + red2[1]);
  short* wr = w8 + ((size_t)h * N_DIM + i) * N_DIM;
  wr[t] = f2bs(e0 * inv);
  wr[t + 128] = f2bs(e1 * inv);
  wr[t + 256] = f2bs(e2 * inv);
}

// ---------------- v = LN(m0) @ wm via MFMA (inline LN), emit vT[h][n][j] ----
__global__ __launch_bounds__(256, 1) void k_vgemm(const float* __restrict__ m0,
                                                  const float* __restrict__ nw,
                                                  const float* __restrict__ nb,
                                                  const short* __restrict__ wm_f,
                                                  short* __restrict__ vT) {
  int blk = blockIdx.x;
  int sblk = blk / 6, j0 = (blk % 6) * 64;
  __shared__ short vt[256 * 64];
  int t = threadIdx.x, wave = t >> 6, lane = t & 63;
  int lg = lane >> 4, l15 = lane & 15;
  size_t rb = (size_t)sblk * N_DIM + j0;
  int rw0 = wave * 16;
  const float* mrow = m0 + (rb + rw0 + l15) * CM;
  float4 x0 = *reinterpret_cast<const float4*>(mrow + lg * 8);
  float4 x1 = *reinterpret_cast<const float4*>(mrow + lg * 8 + 4);
  float4 x2 = *reinterpret_cast<const float4*>(mrow + 32 + lg * 8);
  float4 x3 = *reinterpret_cast<const float4*>(mrow + 32 + lg * 8 + 4);
  float s = x0.x + x0.y + x0.z + x0.w + x1.x + x1.y + x1.z + x1.w +
            x2.x + x2.y + x2.z + x2.w + x3.x + x3.y + x3.z + x3.w;
  float sq = x0.x * x0.x + x0.y * x0.y + x0.z * x0.z + x0.w * x0.w +
             x1.x * x1.x + x1.y * x1.y + x1.z * x1.z + x1.w * x1.w +
             x2.x * x2.x + x2.y * x2.y + x2.z * x2.z + x2.w * x2.w +
             x3.x * x3.x + x3.y * x3.y + x3.z * x3.z + x3.w * x3.w;
  s += __shfl_xor(s, 16); s += __shfl_xor(s, 32);
  sq += __shfl_xor(sq, 16); sq += __shfl_xor(sq, 32);
  float mu = s * (1.0f / CM);
  float var = sq * (1.0f / CM) - mu * mu;
  float rs = rsqrtf(var + 1e-5f);
  float4 g0 = *reinterpret_cast<const float4*>(nw + lg * 8);
  float4 g1 = *reinterpret_cast<const float4*>(nw + lg * 8 + 4);
  float4 g2 = *reinterpret_cast<const float4*>(nw + 32 + lg * 8);
  float4 g3 = *reinterpret_cast<const float4*>(nw + 32 + lg * 8 + 4);
  float4 c0 = *reinterpret_cast<const float4*>(nb + lg * 8);
  float4 c1 = *reinterpret_cast<const float4*>(nb + lg * 8 + 4);
  float4 c2 = *reinterpret_cast<const float4*>(nb + 32 + lg * 8);
  float4 c3 = *reinterpret_cast<const float4*>(nb + 32 + lg * 8 + 4);
  short av[16];
  av[0] = f2bs((x0.x - mu) * rs * g0.x + c0.x);
  av[1] = f2bs((x0.y - mu) * rs * g0.y + c0.y);
  av[2] = f2bs((x0.z - mu) * rs * g0.z + c0.z);
  av[3] = f2bs((x0.w - mu) * rs * g0.w + c0.w);
  av[4] = f2bs((x1.x - mu) * rs * g1.x + c1.x);
  av[5] = f2bs((x1.y - mu) * rs * g1.y + c1.y);
  av[6] = f2bs((x1.z - mu) * rs * g1.z + c1.z);
  av[7] = f2bs((x1.w - mu) * rs * g1.w + c1.w);
  av[8] = f2bs((x2.x - mu) * rs * g2.x + c2.x);
  av[9] = f2bs((x2.y - mu) * rs * g2.y + c2.y);
  av[10] = f2bs((x2.z - mu) * rs * g2.z + c2.z);
  av[11] = f2bs((x2.w - mu) * rs * g2.w + c2.w);
  av[12] = f2bs((x3.x - mu) * rs * g3.x + c3.x);
  av[13] = f2bs((x3.y - mu) * rs * g3.y + c3.y);
  av[14] = f2bs((x3.z - mu) * rs * g3.z + c3.z);
  av[15] = f2bs((x3.w - mu) * rs * g3.w + c3.w);
  bf16x8 a0 = *reinterpret_cast<const bf16x8*>(&av[0]);
  bf16x8 a1 = *reinterpret_cast<const bf16x8*>(&av[8]);
  f32x4 acc[16];
#pragma unroll
  for (int nf = 0; nf < 16; ++nf) acc[nf] = (f32x4){0.f, 0.f, 0.f, 0.f};
#pragma unroll
  for (int nf = 0; nf < 16; ++nf) {
    bf16x8 b0 = *reinterpret_cast<const bf16x8*>(wm_f + ((size_t)nf * 64 + lane) * 8);
    bf16x8 b1 = *reinterpret_cast<const bf16x8*>(wm_f + ((size_t)(16 + nf) * 64 + lane) * 8);
    acc[nf] = __builtin_amdgcn_mfma_f32_16x16x32_bf16(a0, b0, acc[nf], 0, 0, 0);
    acc[nf] = __builtin_amdgcn_mfma_f32_16x16x32_bf16(a1, b1, acc[nf], 0, 0, 0);
  }
#pragma unroll
  for (int nf = 0; nf < 16; ++nf)
#pragma unroll
    for (int r = 0; r < 4; ++r) {
      int jl = rw0 + lg * 4 + r;
      int hd = nf * 16 + l15;
      vt[hd * 64 + jl] = f2bs(acc[nf][r]);
    }
  __syncthreads();
  int h = t >> 5, d = t & 31;
  size_t gbase = ((size_t)h * 16384 + (size_t)sblk * 32 + d) * 384 + j0;
#pragma unroll
  for (int q = 0; q < 8; ++q)
    *reinterpret_cast<float4*>(&vT[gbase + q * 8]) =
        *reinterpret_cast<const float4*>(&vt[t * 64 + q * 8]);
}

// ---------------- o = W @ V per head, MFMA, dbuf prefetch (BJ=32) -----------
__global__ __launch_bounds__(256, 2) void k_ogemm(const short* __restrict__ w8,
                                                  const short* __restrict__ vT,
                                                  bf16* __restrict__ o) {
  int h = blockIdx.y;
  int u = blockIdx.x;
  int gid = (u & 7) * 24 + (u >> 3);   // bijective XCD chunking (192 = 8*24)
  int nb = gid / 3, ib = gid % 3;
  int i0 = ib * 128;
  __shared__ __align__(16) char lds8[49152];  // W: 2x8KB @0, V: 2x16KB @16384
  char* LW = lds8;
  char* LV = lds8 + 16384;
  int t = threadIdx.x, wave = t >> 6, lane = t & 63;
  int lg = lane >> 4, l15 = lane & 15;
  f32x4 acc[8][4];
#pragma unroll
  for (int a = 0; a < 8; ++a)
#pragma unroll
    for (int b = 0; b < 4; ++b) acc[a][b] = (f32x4){0.f, 0.f, 0.f, 0.f};
  const short* Wb = w8 + ((size_t)h * N_DIM + i0) * N_DIM;
  const short* Vb = vT + ((size_t)h * 16384 + (size_t)nb * 256) * N_DIM;

  auto STAGE = [&](int buf, int kt) {
    int j0 = kt * 32;
#pragma unroll
    for (int q = 0; q < 2; ++q) {
      int c = t + q * 256;
      int ri = c >> 2, s = c & 3;
      gl_lds16(Wb + (size_t)ri * N_DIM + j0 + ((s ^ (ri & 3)) << 3),
               LW + buf * 8192 + c * 16);
    }
#pragma unroll
    for (int q = 0; q < 4; ++q) {
      int c = t + q * 256;
      int rn = c >> 2, s = c & 3;
      gl_lds16(Vb + (size_t)rn * N_DIM + j0 + ((s ^ (rn & 3)) << 3),
               LV + buf * 16384 + c * 16);
    }
  };

  STAGE(0, 0);
  __syncthreads();
  for (int kt = 0; kt < 12; ++kt) {
    int cur = kt & 1;
    if (kt < 11) STAGE(cur ^ 1, kt + 1);
    bf16x8 bfr[4];
#pragma unroll
    for (int fn = 0; fn < 4; ++fn) {
      int nl = wave * 64 + fn * 16 + l15;
      bfr[fn] = *reinterpret_cast<const bf16x8*>(
          LV + cur * 16384 + nl * 64 + ((lg * 16) ^ ((nl & 3) << 4)));
    }
#pragma unroll
    for (int fm = 0; fm < 8; ++fm) {
      int il = fm * 16 + l15;
      bf16x8 af = *reinterpret_cast<const bf16x8*>(
          LW + cur * 8192 + il * 64 + ((lg * 16) ^ ((il & 3) << 4)));
#pragma unroll
      for (int fn = 0; fn < 4; ++fn)
        acc[fm][fn] = __builtin_amdgcn_mfma_f32_16x16x32_bf16(
            af, bfr[fn], acc[fm][fn], 0, 0, 0);
    }
    __syncthreads();
  }
#pragma unroll
  for (int fm = 0; fm < 8; ++fm)
#pragma unroll
    for (int fn = 0; fn < 4; ++fn)
#pragma unroll
      for (int r = 0; r < 4; ++r) {
        int i = i0 + fm * 16 + lg * 4 + r;
        int n = nb * 256 + wave * 64 + fn * 16 + l15;
        int s = n >> 5, d = n & 31;
        o[((size_t)s * N_DIM + i) * HD + h * DH + d] = f2bf(acc[fm][fn][r]);
      }
}

// ---------------- pwa out: inline LN; o staged via LDS; MFMA x2 -------------
#define OSTR 264
__global__ __launch_bounds__(256, 1) void k_pwa_out(const float* __restrict__ m0,
                                                    const bf16* __restrict__ o,
                                                    const float* __restrict__ nw,
                                                    const float* __restrict__ nb,
                                                    const short* __restrict__ wg_f,
                                                    const short* __restrict__ wpo_f,
                                                    float* __restrict__ m1out) {
  int blk = blockIdx.x;
  int sblk = blk / 6, j0 = (blk % 6) * 64;
  __shared__ __align__(16) short olds[64 * OSTR];   // 33,792 B (padded o tile)
  __shared__ __align__(16) char hlds[32768];
  int t = threadIdx.x, wave = t >> 6, lane = t & 63;
  int lg = lane >> 4, l15 = lane & 15;
  size_t rb0 = (size_t)sblk * N_DIM + j0;
  size_t rb = rb0 + wave * 16;
#pragma unroll
  for (int q = 0; q < 8; ++q) {
    int f = t + q * 256;
    int row = f >> 5, pos = f & 31;
    *reinterpret_cast<float4*>(&olds[row * OSTR + pos * 8]) =
        *reinterpret_cast<const float4*>((const short*)o + (rb0 + row) * HD + pos * 8);
  }
  const float* mrow = m0 + (rb + l15) * CM;
  float4 x0 = *reinterpret_cast<const float4*>(mrow + lg * 8);
  float4 x1 = *reinterpret_cast<const float4*>(mrow + lg * 8 + 4);
  float4 x2 = *reinterpret_cast<const float4*>(mrow + 32 + lg * 8);
  float4 x3 = *reinterpret_cast<const float4*>(mrow + 32 + lg * 8 + 4);
  float s = x0.x + x0.y + x0.z + x0.w + x1.x + x1.y + x1.z + x1.w +
            x2.x + x2.y + x2.z + x2.w + x3.x + x3.y + x3.z + x3.w;
  float sq = x0.x * x0.x + x0.y * x0.y + x0.z * x0.z + x0.w * x0.w +
             x1.x * x1.x + x1.y * x1.y + x1.z * x1.z + x1.w * x1.w +
             x2.x * x2.x + x2.y * x2.y + x2.z * x2.z + x2.w * x2.w +
             x3.x * x3.x + x3.y * x3.y + x3.z * x3.z + x3.w * x3.w;
  s += __shfl_xor(s, 16); s += __shfl_xor(s, 32);
  sq += __shfl_xor(sq, 16); sq += __shfl_xor(sq, 32);
  float mu = s * (1.0f / CM);
  float var = sq * (1.0f / CM) - mu * mu;
  float rs = rsqrtf(var + 1e-5f);
  float4 g0 = *reinterpret_cast<const float4*>(nw + lg * 8);
  float4 g1 = *reinterpret_cast<const float4*>(nw + lg * 8 + 4);
  float4 g2 = *reinterpret_cast<const float4*>(nw + 32 + lg * 8);
  float4 g3 = *reinterpret_cast<const float4*>(nw + 32 + lg * 8 + 4);
  float4 c0 = *reinterpret_cast<const float4*>(nb + lg * 8);
  float4 c1 = *reinterpret_cast<const float4*>(nb + lg * 8 + 4);
  float4 c2 = *reinterpret_cast<const float4*>(nb + 32 + lg * 8);
  float4 c3 = *reinterpret_cast<const float4*>(nb + 32 + lg * 8 + 4);
  short av[16];
  av[0] = f2bs((x0.x - mu) * rs * g0.x + c0.x);
  av[1] = f2bs((x0.y - mu) * rs * g0.y + c0.y);
  av[2] = f2bs((x0.z - mu) * rs * g0.z + c0.z);
  av[3] = f2bs((x0.w - mu) * rs * g0.w + c0.w);
  av[4] = f2bs((x1.x - mu) * rs * g1.x + c1.x);
  av[5] = f2bs((x1.y - mu) * rs * g1.y + c1.y);
  av[6] = f2bs((x1.z - mu) * rs * g1.z + c1.z);
  av[7] = f2bs((x1.w - mu) * rs * g1.w + c1.w);
  av[8] = f2bs((x2.x - mu) * rs * g2.x + c2.x);
  av[9] = f2bs((x2.y - mu) * rs * g2.y + c2.y);
  av[10] = f2bs((x2.z - mu) * rs * g2.z + c2.z);
  av[11] = f2bs((x2.w - mu) * rs * g2.w + c2.w);
  av[12] = f2bs((x3.x - mu) * rs * g3.x + c3.x);
  av[13] = f2bs((x3.y - mu) * rs * g3.y + c3.y);
  av[14] = f2bs((x3.z - mu) * rs * g3.z + c3.z);
  av[15] = f2bs((x3.w - mu) * rs * g3.w + c3.w);
  bf16x8 a0 = *reinterpret_cast<const bf16x8*>(&av[0]);
  bf16x8 a1 = *reinterpret_cast<const bf16x8*>(&av[8]);
  f32x4 acc[16];
#pragma unroll
  for (int nf = 0; nf < 16; ++nf) acc[nf] = (f32x4){0.f, 0.f, 0.f, 0.f};
#pragma unroll
  for (int nf = 0; nf < 16; ++nf) {
    bf16x8 b0 = *reinterpret_cast<const bf16x8*>(wg_f + ((size_t)nf * 64 + lane) * 8);
    bf16x8 b1 = *reinterpret_cast<const bf16x8*>(wg_f + ((size_t)(16 + nf) * 64 + lane) * 8);
    acc[nf] = __builtin_amdgcn_mfma_f32_16x16x32_bf16(a0, b0, acc[nf], 0, 0, 0);
    acc[nf] = __builtin_amdgcn_mfma_f32_16x16x32_bf16(a1, b1, acc[nf], 0, 0, 0);
  }
  __syncthreads();  // olds staged (all waves), safe to read
  char* hb = hlds + wave * 8192;
#pragma unroll
  for (int nf = 0; nf < 16; ++nf)
#pragma unroll
    for (int r = 0; r < 4; ++r) {
      int row = lg * 4 + r;
      float x = acc[nf][r];
      float g = 1.0f / (1.0f + __expf(-x));
      float ov = bf2f(*reinterpret_cast<const bf16*>(
          &olds[(wave * 16 + row) * OSTR + nf * 16 + l15]));
      *reinterpret_cast<short*>(
          hb + row * 512 + (((nf * 16 + l15) * 2) ^ ((row & 7) << 4))) = f2bs(g * ov);
    }
  __syncthreads();
  f32x4 acc3[4];
#pragma unroll
  for (int nf2 = 0; nf2 < 4; ++nf2) acc3[nf2] = (f32x4){0.f, 0.f, 0.f, 0.f};
#pragma unroll
  for (int ks2 = 0; ks2 < 8; ++ks2) {
    bf16x8 a2 = *reinterpret_cast<const bf16x8*>(
        hb + l15 * 512 + ((ks2 * 64 + lg * 16) ^ ((l15 & 7) << 4)));
#pragma unroll
    for (int nf2 = 0; nf2 < 4; ++nf2) {
      bf16x8 b = *reinterpret_cast<const bf16x8*>(
          wpo_f + ((size_t)(ks2 * 4 + nf2) * 64 + lane) * 8);
      acc3[nf2] = __builtin_amdgcn_mfma_f32_16x16x32_bf16(a2, b, acc3[nf2], 0, 0, 0);
    }
  }
#pragma unroll
  for (int nf2 = 0; nf2 < 4; ++nf2)
#pragma unroll
    for (int r = 0; r < 4; ++r) {
      size_t a = (rb + lg * 4 + r) * CM + nf2 * 16 + l15;
      m1out[a] = m0[a] + acc3[nf2][r];
    }
}

// ---------------- transition via MFMA: m2 = m1 + (silu(tn@w1)*(tn@w2))@w3 ---
__global__ __launch_bounds__(256, 1) void k_transition(const float* __restrict__ nw,
                                                       const float* __restrict__ nb,
                                                       const short* __restrict__ w1_f,
                                                       const short* __restrict__ w2_f,
                                                       const short* __restrict__ w3_f,
                                                       float* __restrict__ mio) {
  __shared__ __align__(16) char hlds[32768];
  int t = threadIdx.x, wave = t >> 6, lane = t & 63;
  int lg = lane >> 4, l15 = lane & 15;
  size_t rb = (size_t)blockIdx.x * 64 + wave * 16;
  const float* mrow = mio + (rb + l15) * CM;
  float4 x0 = *reinterpret_cast<const float4*>(mrow + lg * 8);
  float4 x1 = *reinterpret_cast<const float4*>(mrow + lg * 8 + 4);
  float4 x2 = *reinterpret_cast<const float4*>(mrow + 32 + lg * 8);
  float4 x3 = *reinterpret_cast<const float4*>(mrow + 32 + lg * 8 + 4);
  float s = x0.x + x0.y + x0.z + x0.w + x1.x + x1.y + x1.z + x1.w +
            x2.x + x2.y + x2.z + x2.w + x3.x + x3.y + x3.z + x3.w;
  float sq = x0.x * x0.x + x0.y * x0.y + x0.z * x0.z + x0.w * x0.w +
             x1.x * x1.x + x1.y * x1.y + x1.z * x1.z + x1.w * x1.w +
             x2.x * x2.x + x2.y * x2.y + x2.z * x2.z + x2.w * x2.w +
             x3.x * x3.x + x3.y * x3.y + x3.z * x3.z + x3.w * x3.w;
  s += __shfl_xor(s, 16); s += __shfl_xor(s, 32);
  sq += __shfl_xor(sq, 16); sq += __shfl_xor(sq, 32);
  float mu = s * (1.0f / CM);
  float var = sq * (1.0f / CM) - mu * mu;
  float rs = rsqrtf(var + 1e-5f);
  float4 g0 = *reinterpret_cast<const float4*>(nw + lg * 8);
  float4 g1 = *reinterpret_cast<const float4*>(nw + lg * 8 + 4);
  float4 g2 = *reinterpret_cast<const float4*>(nw + 32 + lg * 8);
  float4 g3 = *reinterpret_cast<const float4*>(nw + 32 + lg * 8 + 4);
  float4 c0 = *reinterpret_cast<const float4*>(nb + lg * 8);
  float4 c1 = *reinterpret_cast<const float4*>(nb + lg * 8 + 4);
  float4 c2 = *reinterpret_cast<const float4*>(nb + 32 + lg * 8);
  float4 c3 = *reinterpret_cast<const float4*>(nb + 32 + lg * 8 + 4);
  short av[16];
  av[0] = f2bs((x0.x - mu) * rs * g0.x + c0.x);
  av[1] = f2bs((x0.y - mu) * rs * g0.y + c0.y);
  av[2] = f2bs((x0.z - mu) * rs * g0.z + c0.z);
  av[3] = f2bs((x0.w - mu) * rs * g0.w + c0.w);
  av[4] = f2bs((x1.x - mu) * rs * g1.x + c1.x);
  av[5] = f2bs((x1.y - mu) * rs * g1.y + c1.y);
  av[6] = f2bs((x1.z - mu) * rs * g1.z + c1.z);
  av[7] = f2bs((x1.w - mu) * rs * g1.w + c1.w);
  av[8] = f2bs((x2.x - mu) * rs * g2.x + c2.x);
  av[9] = f2bs((x2.y - mu) * rs * g2.y + c2.y);
  av[10] = f2bs((x2.z - mu) * rs * g2.z + c2.z);
  av[11] = f2bs((x2.w - mu) * rs * g2.w + c2.w);
  av[12] = f2bs((x3.x - mu) * rs * g3.x + c3.x);
  av[13] = f2bs((x3.y - mu) * rs * g3.y + c3.y);
  av[14] = f2bs((x3.z - mu) * rs * g3.z + c3.z);
  av[15] = f2bs((x3.w - mu) * rs * g3.w + c3.w);
  bf16x8 a0 = *reinterpret_cast<const bf16x8*>(&av[0]);
  bf16x8 a1 = *reinterpret_cast<const bf16x8*>(&av[8]);
  f32x4 acc1[16], acc2[16];
#pragma unroll
  for (int nf = 0; nf < 16; ++nf) {
    acc1[nf] = (f32x4){0.f, 0.f, 0.f, 0.f};
    acc2[nf] = (f32x4){0.f, 0.f, 0.f, 0.f};
  }
#pragma unroll
  for (int nf = 0; nf < 16; ++nf) {
    bf16x8 b10 = *reinterpret_cast<const bf16x8*>(w1_f + ((size_t)nf * 64 + lane) * 8);
    bf16x8 b11 = *reinterpret_cast<const bf16x8*>(w1_f + ((size_t)(16 + nf) * 64 + lane) * 8);
    acc1[nf] = __builtin_amdgcn_mfma_f32_16x16x32_bf16(a0, b10, acc1[nf], 0, 0, 0);
    acc1[nf] = __builtin_amdgcn_mfma_f32_16x16x32_bf16(a1, b11, acc1[nf], 0, 0, 0);
    bf16x8 b20 = *reinterpret_cast<const bf16x8*>(w2_f + ((size_t)nf * 64 + lane) * 8);
    bf16x8 b21 = *reinterpret_cast<const bf16x8*>(w2_f + ((size_t)(16 + nf) * 64 + lane) * 8);
    acc2[nf] = __builtin_amdgcn_mfma_f32_16x16x32_bf16(a0, b20, acc2[nf], 0, 0, 0);
    acc2[nf] = __builtin_amdgcn_mfma_f32_16x16x32_bf16(a1, b21, acc2[nf], 0, 0, 0);
  }
  char* hb = hlds + wave * 8192;
#pragma unroll
  for (int nf = 0; nf < 16; ++nf)
#pragma unroll
    for (int r = 0; r < 4; ++r) {
      int row = lg * 4 + r;
      float x = acc1[nf][r];
      float h = (x / (1.0f + __expf(-x))) * acc2[nf][r];
      *reinterpret_cast<short*>(
          hb + row * 512 + (((nf * 16 + l15) * 2) ^ ((row & 7) << 4))) = f2bs(h);
    }
  __syncthreads();
  f32x4 acc3[4];
#pragma unroll
  for (int nf2 = 0; nf2 < 4; ++nf2) acc3[nf2] = (f32x4){0.f, 0.f, 0.f, 0.f};
#pragma unroll
  for (int ks2 = 0; ks2 < 8; ++ks2) {
    bf16x8 a2 = *reinterpret_cast<const bf16x8*>(
        hb + l15 * 512 + ((ks2 * 64 + lg * 16) ^ ((l15 & 7) << 4)));
#pragma unroll
    for (int nf2 = 0; nf2 < 4; ++nf2) {
      bf16x8 b = *reinterpret_cast<const bf16x8*>(
          w3_f + ((size_t)(ks2 * 4 + nf2) * 64 + lane) * 8);
      acc3[nf2] = __builtin_amdgcn_mfma_f32_16x16x32_bf16(a2, b, acc3[nf2], 0, 0, 0);
    }
  }
#pragma unroll
  for (int nf2 = 0; nf2 < 4; ++nf2)
#pragma unroll
    for (int r = 0; r < 4; ++r) {
      size_t a = (rb + lg * 4 + r) * CM + nf2 * 16 + l15;
      mio[a] = mio[a] + acc3[nf2][r];
    }
}

// ---------------- opm a/b: LN(m2)@wa/wb -> fp8 e4m3, FRAGMENT-PACKED --------
__global__ __launch_bounds__(256) void k_opm_ab(const float* __restrict__ m2,
                                                const float* __restrict__ nw,
                                                const float* __restrict__ nb,
                                                const float* __restrict__ wa,
                                                const float* __restrict__ wb,
                                                unsigned char* __restrict__ at8,
                                                unsigned char* __restrict__ bt8) {
  int bix = blockIdx.x;
  int sg = bix / N_DIM;
  int i = bix - sg * N_DIM;
  __shared__ float on[64][65];
  __shared__ float wl[2][64][36];
  __shared__ float tl[2][32][65];
  int t = threadIdx.x, w = t >> 6, lane = t & 63;
  float gw = nw[lane], gb = nb[lane];
  for (int rr = 0; rr < 16; ++rr) {
    int sl = w * 16 + rr;
    float x = m2[((size_t)(sg * 64 + sl) * N_DIM + i) * CM + lane];
    float s = x, sq = x * x;
#pragma unroll
    for (int off = 32; off; off >>= 1) {
      s += __shfl_xor(s, off);
      sq += __shfl_xor(sq, off);
    }
    float mu = s * (1.0f / CM);
    float var = sq * (1.0f / CM) - mu * mu;
    float rs = rsqrtf(var + 1e-5f);
    on[sl][lane] = (x - mu) * rs * gw + gb;
  }
  for (int idx = t; idx < 2048; idx += 256) {
    int k = idx >> 5, c = idx & 31;
    wl[0][k][c] = wa[idx];
    wl[1][k][c] = wb[idx];
  }
  __syncthreads();
  int s = t >> 2, c0 = (t & 3) * 8;
  float accA[8], accB[8];
#pragma unroll
  for (int j = 0; j < 8; ++j) { accA[j] = 0.0f; accB[j] = 0.0f; }
  for (int k = 0; k < 64; ++k) {
    float ov = on[s][k];
#pragma unroll
    for (int j = 0; j < 8; ++j) {
      accA[j] += ov * wl[0][k][c0 + j];
      accB[j] += ov * wl[1][k][c0 + j];
    }
  }
#pragma unroll
  for (int j = 0; j < 8; ++j) {
    tl[0][c0 + j][s] = accA[j];
    tl[1][c0 + j][s] = accB[j];
  }
  __syncthreads();
  int cc = t >> 3, s8 = (t & 7) * 8;
  int lane8 = ((((s8 & 31) >> 3) * 16) + (cc & 15)) * 8;
  int kg = sg * 2 + (s8 >> 5);
  size_t obA = (size_t)(i >> 3) * 131072 + (size_t)kg * 8192 +
               (size_t)((i & 7) * 2 + (cc >> 4)) * 512 + lane8;
  size_t obB = (size_t)(i >> 2) * 65536 + (size_t)kg * 4096 +
               (size_t)((i & 3) * 2 + (cc >> 4)) * 512 + lane8;
  unsigned int p0 = 0, p1 = 0;
  p0 = __builtin_amdgcn_cvt_pk_fp8_f32(tl[0][cc][s8 + 0], tl[0][cc][s8 + 1], p0, false);
  p0 = __builtin_amdgcn_cvt_pk_fp8_f32(tl[0][cc][s8 + 2], tl[0][cc][s8 + 3], p0, true);
  p1 = __builtin_amdgcn_cvt_pk_fp8_f32(tl[0][cc][s8 + 4], tl[0][cc][s8 + 5], p1, false);
  p1 = __builtin_amdgcn_cvt_pk_fp8_f32(tl[0][cc][s8 + 6], tl[0][cc][s8 + 7], p1, true);
  uint2 pa = {p0, p1};
  *reinterpret_cast<uint2*>(at8 + obA) = pa;
  p0 = 0; p1 = 0;
  p0 = __builtin_amdgcn_cvt_pk_fp8_f32(tl[1][cc][s8 + 0], tl[1][cc][s8 + 1], p0, false);
  p0 = __builtin_amdgcn_cvt_pk_fp8_f32(tl[1][cc][s8 + 2], tl[1][cc][s8 + 3], p0, true);
  p1 = __builtin_amdgcn_cvt_pk_fp8_f32(tl[1][cc][s8 + 4], tl[1][cc][s8 + 5], p1, false);
  p1 = __builtin_amdgcn_cvt_pk_fp8_f32(tl[1][cc][s8 + 6], tl[1][cc][s8 + 7], p1, true);
  uint2 pb = {p0, p1};
  *reinterpret_cast<uint2*>(bt8 + obB) = pb;
}

// ---------------- wo8: fragment-packed wo (fp8 e4m3), permuted k=(d<<5)|c ---
__global__ __launch_bounds__(256) void k_wot(const float* __restrict__ wo,
                                             unsigned char* __restrict__ wo8) {
  int tg = blockIdx.x * 256 + threadIdx.x;   // 64 blocks -> 16384 fragments
  int frag = tg >> 6, lane = tg & 63;
  int eblk = frag >> 5, kc = frag & 31;
  int e = eblk * 16 + (lane & 15);
  int kbase = kc * 32 + (lane >> 4) * 8;
  float v[8];
#pragma unroll
  for (int j = 0; j < 8; ++j) {
    int q = kbase + j;                       // permuted index cd2 = (d<<5)|c
    int row = ((q & 31) << 5) | (q >> 5);    // original wo row = c*32 + d
    v[j] = wo[(size_t)row * CZ + e];
  }
  unsigned int p0 = 0, p1 = 0;
  p0 = __builtin_amdgcn_cvt_pk_fp8_f32(v[0], v[1], p0, false);
  p0 = __builtin_amdgcn_cvt_pk_fp8_f32(v[2], v[3], p0, true);
  p1 = __builtin_amdgcn_cvt_pk_fp8_f32(v[4], v[5], p1, false);
  p1 = __builtin_amdgcn_cvt_pk_fp8_f32(v[6], v[7], p1, true);
  uint2 pk = {p0, p1};
  *reinterpret_cast<uint2*>(wo8 + (size_t)tg * 8) = pk;
}

// ---------------- OPM: fp8 MFMA 256x128, fragment LDS, fp8 P epilogue -------
#define PS 1064   // P row stride bytes (266 dwords; gcd(266,32)=2 -> ~free)
__global__ __launch_bounds__(512, 2) void k_opm(const unsigned char* __restrict__ at8,
                                                const unsigned char* __restrict__ bt8,
                                                const unsigned char* __restrict__ wo8,
                                                const float* __restrict__ bo,
                                                const float* __restrict__ z0,
                                                float* __restrict__ z1) {
  // XCD mapping: xcd owns bm in [xcd*6, xcd*6+6), traversal bn-outer (4608=8*576)
  int g = blockIdx.x;
  int xcd = g & 7, u = g >> 3;
  int bn = u / 6;
  int bm = xcd * 6 + (u - bn * 6);
  // A: 2x16KB @0, B: 2x8KB @32768; P fp8 (32 x 1064 = 34048 B) overlays
  __shared__ __align__(16) char lds8[49152];
  char* LA = lds8;
  char* LB = lds8 + 32768;
  int t = threadIdx.x, wave = t >> 6, lane = t & 63;
  int wm2 = wave >> 1, wn2 = wave & 1;   // 4m x 2n wave grid, 64x64 tiles
  int lg = lane >> 4, l15 = lane & 15;
  f32x4 acc[4][4];
#pragma unroll
  for (int a = 0; a < 4; ++a)
#pragma unroll
    for (int b = 0; b < 4; ++b) acc[a][b] = (f32x4){0.f, 0.f, 0.f, 0.f};
  const unsigned char* A = at8 + (size_t)bm * 131072;   // [kg16][mg16][512]
  const unsigned char* B = bt8 + (size_t)bn * 65536;    // [kg16][ng8][512]

  auto STAGE = [&](int buf, int kt) {
    gl_lds16(A + (size_t)kt * 16384 + t * 16, LA + buf * 16384 + t * 16);
    gl_lds16(A + (size_t)kt * 16384 + 8192 + t * 16,
             LA + buf * 16384 + 8192 + t * 16);
    gl_lds16(B + (size_t)kt * 8192 + t * 16, LB + buf * 8192 + t * 16);
  };

  STAGE(0, 0);
  __syncthreads();
  for (int kt = 0; kt < 8; ++kt) {
    int cur = kt & 1;
    if (kt < 7) STAGE(cur ^ 1, kt + 1);
    const char* LAc = LA + cur * 16384;
    const char* LBc = LB + cur * 8192;
#pragma unroll
    for (int ks = 0; ks < 2; ++ks) {
      i64 bfr[4];
#pragma unroll
      for (int fn = 0; fn < 4; ++fn)
        bfr[fn] = *reinterpret_cast<const i64*>(
            LBc + ks * 4096 + (wn2 * 4 + fn) * 512 + lane * 8);
#pragma unroll
      for (int fm = 0; fm < 4; ++fm) {
        i64 af = *reinterpret_cast<const i64*>(
            LAc + ks * 8192 + (wm2 * 4 + fm) * 512 + lane * 8);
#pragma unroll
        for (int fn = 0; fn < 4; ++fn)
          acc[fm][fn] = __builtin_amdgcn_mfma_f32_16x16x32_fp8_fp8(
              af, bfr[fn], acc[fm][fn], 0, 0, 0);
      }
    }
    __syncthreads();
  }

  // --- one-shot P write (fp8, scaled x1024/512=2): P[32 pairs][PS bytes] ---
  unsigned char* P = (unsigned char*)lds8;
  const float sc = 2.0f;          // op*1024 when combined with 1/512
#pragma unroll
  for (int fm = 0; fm < 4; ++fm)
#pragma unroll
    for (int fn = 0; fn < 4; ++fn) {
      int m = wm2 * 64 + fm * 16 + lg * 4;   // 4 consecutive m (r)
      int n = wn2 * 64 + fn * 16 + l15;
      int prow = (m >> 5) * 4 + (n >> 5);
      int cd2 = ((n & 31) << 5) | (m & 31);
      unsigned int p0 = 0;
      p0 = __builtin_amdgcn_cvt_pk_fp8_f32(acc[fm][fn][0] * sc,
                                           acc[fm][fn][1] * sc, p0, false);
      p0 = __builtin_amdgcn_cvt_pk_fp8_f32(acc[fm][fn][2] * sc,
                                           acc[fm][fn][3] * sc, p0, true);
      *reinterpret_cast<unsigned int*>(P + prow * PS + cd2) = p0;
    }
  __syncthreads();

  // --- projection (fp8 x fp8): 2 pair-groups x 8 e-blocks, 8 waves ---
  int eblk = wave;
#pragma unroll
  for (int it = 0; it < 2; ++it) {
    f32x4 pacc = (f32x4){0.f, 0.f, 0.f, 0.f};
    for (int c0 = 0; c0 < 1024; c0 += 32) {
      i64 pa = *reinterpret_cast<const i64*>(
          P + (it * 16 + l15) * PS + c0 + lg * 8);
      i64 pb = *reinterpret_cast<const i64*>(
          wo8 + ((size_t)(eblk * 32 + (c0 >> 5)) * 64 + lane) * 8);
      pacc = __builtin_amdgcn_mfma_f32_16x16x32_fp8_fp8(pa, pb, pacc, 0, 0, 0);
    }
    int e = eblk * 16 + l15;
    float bov = bo[e];
#pragma unroll
    for (int r = 0; r < 4; ++r) {
      int prow = it * 16 + lg * 4 + r;
      int gi = bm * 8 + (prow >> 2), gj = bn * 4 + (prow & 3);
      size_t addr = ((size_t)gi * N_DIM + gj) * CZ + e;
      z1[addr] = z0[addr] + pacc[r] * (1.0f / 1024.0f) + bov;
    }
  }
}

// ---------------------------------------------------------------------------
extern "C" void kernel_launch(void* const* d_in, const int* in_sizes, int n_in,
                              void* d_out, int out_size, void* d_ws, size_t ws_size,
                              hipStream_t stream) {
  const float* m0 = (const float*)d_in[0];
  const float* z0 = (const float*)d_in[1];
  const float* pwa_nm_w = (const float*)d_in[2];
  const float* pwa_nm_b = (const float*)d_in[3];
  const float* pwa_nz_w = (const float*)d_in[4];
  const float* pwa_nz_b = (const float*)d_in[5];
  const float* pwa_wm = (const float*)d_in[6];
  const float* pwa_wg = (const float*)d_in[7];
  const float* pwa_wz = (const float*)d_in[8];
  const float* pwa_wo = (const float*)d_in[9];
  const float* tr_nw = (const float*)d_in[10];
  const float* tr_nb = (const float*)d_in[11];
  const float* tr_w1 = (const float*)d_in[12];
  const float* tr_w2 = (const float*)d_in[13];
  const float* tr_w3 = (const float*)d_in[14];
  const float* opm_nw = (const float*)d_in[15];
  const float* opm_nb = (const float*)d_in[16];
  const float* opm_wa = (const float*)d_in[17];
  const float* opm_wb = (const float*)d_in[18];
  const float* opm_wo = (const float*)d_in[19];
  const float* opm_bo = (const float*)d_in[20];

  char* ws = (char*)d_ws;
  float* wbuf = (float*)(ws + 25165824);         //  4,718,592 B
  short* vT = (short*)(ws + 29884416);           // 100,663,296 B
  bf16* o = (bf16*)(ws + 130547712);             // 100,663,296 B
  // reuse dead vT region after k_ogemm:
  unsigned char* at8 = (unsigned char*)(ws + 29884416);  // 6,291,456 B
  unsigned char* bt8 = at8 + 6291456;                    // 6,291,456 B
  unsigned char* wo8 = (unsigned char*)(ws + 55050240);  //   131,072 B
  short* wz_f = (short*)(ws + 55312384);                 //     4,096 B

  float* m_out = (float*)d_out;
  float* z1 = m_out + (size_t)S_DIM * N_DIM * CM;
  // scratch in the z1 region of d_out (dead until k_opm overwrites all of z1)
  short* packW = (short*)z1;                     // 6 x 32 KB
  short* wm_f = packW;
  short* wg_f = packW + 16384;
  short* w1_f = packW + 32768;
  short* w2_f = packW + 49152;
  short* wpo_f = packW + 65536;
  short* w3_f = packW + 81920;
  short* w8 = (short*)((char*)z1 + 262144);      // 2,359,296 B (bf16 softmax W)

  k_wprep<<<49, 256, 0, stream>>>(pwa_wm, pwa_wg, tr_w1, tr_w2, pwa_wo, tr_w3,
                                  pwa_wz, packW, wz_f);
  k_zb<<<2304, 256, 0, stream>>>(z0, pwa_nz_w, pwa_nz_b, wz_f, wbuf);
  k_softmax<<<3072, 128, 0, stream>>>(wbuf, w8);
  k_vgemm<<<3072, 256, 0, stream>>>(m0, pwa_nm_w, pwa_nm_b, wm_f, vT);
  k_ogemm<<<dim3(192, 8), 256, 0, stream>>>(w8, vT, o);
  k_pwa_out<<<3072, 256, 0, stream>>>(m0, o, pwa_nm_w, pwa_nm_b, wg_f, wpo_f, m_out);
  k_wot<<<64, 256, 0, stream>>>(opm_wo, wo8);
  k_transition<<<3072, 256, 0, stream>>>(tr_nw, tr_nb, w1_f, w2_f, w3_f, m_out);
  k_opm_ab<<<3072, 256, 0, stream>>>(m_out, opm_nw, opm_nb, opm_wa, opm_wb, at8, bt8);
  k_opm<<<4608, 512, 0, stream>>>(at8, bt8, wo8, opm_bo, z0, z1);
}